// Round 1
// baseline (6150.535 us; speedup 1.0000x reference)
//
#include <hip/hip_runtime.h>
#include <math.h>

// stacked_rnn R7: flat epoch barrier.
// = R6 (proven protocol: relaxed-atomic h stores + vmcnt(0) flush + wave-0
//   agent-acquire fence) with the two-level aggregator barrier (8 RMW lines +
//   bid0 broadcast flag) replaced by a flat per-block tag array:
//   - arrive: tid0 STORES etag to cnt[bid] (no RMW, no same-line serialization)
//   - detect: wave 0 of EVERY block sweeps all nblk tags with coherent loads
//     (4 loads/lane at nblk=256, 8 cache lines, parallel at LLC), compare
//     MONOTONIC (>= etag) since a block may run 1 epoch ahead (ping-pong
//     buffers give distance 2, so skew 1 is safe — same as R6).
//   Removes 2-3 serialized LLC round-trips per epoch from the critical path.

typedef __bf16 bf16;
typedef __bf16 bf16x8 __attribute__((ext_vector_type(8)));
typedef float floatx4 __attribute__((ext_vector_type(4)));
typedef unsigned long long ull;

#define B_   128
#define T_   256
#define H_   1024
#define I_   150
#define KX_  160
#define C_   60
#define K1LDS 1280   // layer-1 LDS row width in elems
#define K2LDS 2048   // layer-2 LDS row width
#define NLINES 16    // zeroed tag region: NLINES*CSTRIDE u32 = 4KB
#define CSTRIDE 64

template<int N> struct IC { static constexpr int value = N; };

__device__ __forceinline__ float sigmoidf_(float x) { return 1.f / (1.f + expf(-x)); }

// ---------------- conversion / init kernel ----------------
__global__ __launch_bounds__(256)
void convert_all(const float* __restrict__ x,
                 const float* __restrict__ h1in, const float* __restrict__ h2in,
                 bf16* __restrict__ xb, bf16* __restrict__ h1b0, bf16* __restrict__ h2b0,
                 unsigned* __restrict__ cnt)
{
    const size_t nXB = (size_t)T_ * B_ * KX_;   // 5242880
    const size_t nHC = (size_t)B_ * H_;         // 131072
    size_t idx = (size_t)blockIdx.x * 256 + threadIdx.x;

    if (idx < nXB) {                            // x [B][T][150] -> xb [T][B][160]
        size_t t = idx / (B_ * KX_);
        size_t r = idx - t * (B_ * KX_);
        size_t b = r / KX_, k = r - b * KX_;
        xb[idx] = (k < I_) ? (bf16)x[(b * T_ + t) * I_ + k] : (bf16)0.f;
        return;
    }
    idx -= nXB;
    if (idx < nHC) { h1b0[idx] = (bf16)h1in[idx]; return; }
    idx -= nHC;
    if (idx < nHC) { h2b0[idx] = (bf16)h2in[idx]; return; }
    idx -= nHC;
    if (idx < NLINES * CSTRIDE) cnt[idx] = 0u;
}

// ---------------- persistent LSTM kernel ----------------
// NCOLS=32 -> 256 blocks/128KiB LDS; NCOLS=16 -> 512 blocks/64KiB LDS.
// layer = (bid>>3)&1, slice = (bid&7)|((bid>>4)<<3).
// cnt[0..nblk): per-block epoch tags (monotonic).
template<int NCOLS>
__global__ __launch_bounds__(256, 1)
void rnn_persistent(const bf16* __restrict__ xb,
                    bf16* __restrict__ h1b0, bf16* __restrict__ h1b1,
                    bf16* __restrict__ h2b0, bf16* __restrict__ h2b1,
                    const float* __restrict__ c1in, const float* __restrict__ c2in,
                    const float* __restrict__ Wih1, const float* __restrict__ Whh1,
                    const float* __restrict__ bih1, const float* __restrict__ bhh1,
                    const float* __restrict__ Wih2, const float* __restrict__ Whh2,
                    const float* __restrict__ bih2, const float* __restrict__ bhh2,
                    const float* __restrict__ Wfc, const float* __restrict__ bfc,
                    float* __restrict__ out, unsigned* __restrict__ cnt, int nblk)
{
    constexpr int NHC = NCOLS / 4;      // h-cols per block
    constexpr int NT  = NCOLS / 16;     // N-tiles (2 or 1)
    constexpr int GPR = NHC / 4;        // 8B col-groups per row (2 or 1)
    extern __shared__ bf16 lds[];
    __shared__ __align__(16) bf16 hst[4][32][NHC];   // epilogue staging

    const int tid   = threadIdx.x;
    const int bid   = blockIdx.x;
    const int layer = (bid >> 3) & 1;
    const int slice = (bid & 7) | ((bid >> 4) << 3);
    const int n0h   = slice * NHC;
    const int KLDS  = layer ? K2LDS : K1LDS;

    // ---- stage weights fp32->bf16 into swizzled LDS (once) ----
    {
        const int cpr = KLDS >> 3;              // 16B chunks per row
        const int total = NCOLS * cpr;
        for (int ci = tid; ci < total; ci += 256) {
            int r = ci / cpr, c = ci - r * cpr;
            int g = r / NHC, j = r - g * NHC;
            int grow = (g << 10) + n0h + j;
            int k0 = c << 3;
            float v[8];
#pragma unroll
            for (int u = 0; u < 8; ++u) {
                int k = k0 + u;
                if (layer == 0)
                    v[u] = (k < I_) ? Wih1[(size_t)grow * I_ + k]
                         : (k < KX_) ? 0.f
                         : (k < KX_ + H_) ? Whh1[(size_t)grow * H_ + (k - KX_)] : 0.f;
                else
                    v[u] = (k < H_) ? Wih2[(size_t)grow * H_ + k]
                                    : Whh2[(size_t)grow * H_ + (k - H_)];
            }
            int cs = (c & ~15) | ((c ^ r) & 15);      // XOR swizzle
            bf16* dst = lds + (size_t)r * KLDS + (cs << 3);
#pragma unroll
            for (int u = 0; u < 8; ++u) dst[u] = (bf16)v[u];
        }
    }
    __syncthreads();

    const int lane = tid & 63;
    const int wv   = tid >> 6;
    const int jj   = lane & (NHC - 1);
    const int quad = lane >> 4;

    float4 bias;
    {
        const float* bi = layer ? bih2 : bih1;
        const float* bh = layer ? bhh2 : bhh1;
        int col = n0h + jj;
        bias.x = bi[col] + bh[col];
        bias.y = bi[col + H_] + bh[col + H_];
        bias.z = bi[col + 2 * H_] + bh[col + 2 * H_];
        bias.w = bi[col + 3 * H_] + bh[col + 3 * H_];
    }

    float creg[4];
    {
        const float* cin = layer ? c2in : c1in;
        if constexpr (NCOLS == 32) {
            int dup = (lane >> 3) & 1;
#pragma unroll
            for (int t = 0; t < 2; ++t)
#pragma unroll
                for (int rp = 0; rp < 2; ++rp) {
                    int r = rp * 2 + dup;
                    int row = wv * 32 + t * 16 + quad * 4 + r;
                    creg[t * 2 + rp] = cin[(size_t)row * H_ + n0h + jj];
                }
        } else {
            int r = (lane >> 2) & 3;
#pragma unroll
            for (int t = 0; t < 2; ++t) {
                int row = wv * 32 + t * 16 + quad * 4 + r;
                creg[t] = cin[(size_t)row * H_ + n0h + jj];
            }
        }
    }

    floatx4 acc[2][NT];

    // chunked K-segment: batch up to 16 k-steps (32 global loads) into
    // registers BEFORE consuming -> post-invalidate misses overlap.
    auto seg = [&](const bf16* A, int ldA, auto nksC, int ksBase) {
        constexpr int NKS = decltype(nksC)::value;
        constexpr int CH  = NKS < 16 ? NKS : 16;
        const int arow = wv * 32 + (lane & 15);
        const bf16* a0 = A + (size_t)arow * ldA + quad * 8;
        const bf16* a1 = a0 + 16 * ldA;
        for (int blk = 0; blk < NKS; blk += CH) {
            bf16x8 a0r[CH], a1r[CH];
#pragma unroll
            for (int i = 0; i < CH; ++i) {
                a0r[i] = *(const bf16x8*)(a0 + (blk + i) * 32);
                a1r[i] = *(const bf16x8*)(a1 + (blk + i) * 32);
            }
#pragma unroll
            for (int i = 0; i < CH; ++i) {
                int c = (ksBase + blk + i) * 4 + quad;
#pragma unroll
                for (int t = 0; t < NT; ++t) {
                    int r = t * 16 + (lane & 15);
                    int cs = (c & ~15) | ((c ^ r) & 15);
                    bf16x8 bfr = *(const bf16x8*)(lds + (size_t)r * KLDS + (cs << 3));
                    acc[0][t] = __builtin_amdgcn_mfma_f32_16x16x32_bf16(a0r[i], bfr, acc[0][t], 0, 0, 0);
                    acc[1][t] = __builtin_amdgcn_mfma_f32_16x16x32_bf16(a1r[i], bfr, acc[1][t], 0, 0, 0);
                }
            }
        }
    };

    for (int e = 0; e <= T_; ++e) {
        const bool active = layer == 0 ? (e < T_) : (e >= 1);
        if (active) {
#pragma unroll
            for (int t = 0; t < 2; ++t)
#pragma unroll
                for (int u = 0; u < NT; ++u) acc[t][u] = (floatx4){0.f, 0.f, 0.f, 0.f};

            const bf16* h1r = (e & 1) ? h1b1 : h1b0;         // h1^(e)
            if (layer == 0) {
                const bf16* xt = xb + (size_t)e * B_ * KX_;
                seg(xt, KX_, IC<5>{}, 0);
                seg(h1r, H_, IC<32>{}, 5);
            } else {
                const bf16* h2r = (e & 1) ? h2b0 : h2b1;     // h2^(e-1)
                seg(h1r, H_, IC<32>{}, 0);
                seg(h2r, H_, IC<32>{}, 32);
            }
            bf16* hw = (layer == 0) ? ((e & 1) ? h1b0 : h1b1)   // h1^(e+1)
                                    : ((e & 1) ? h2b1 : h2b0);  // h2^(e)

            // epilogue: shfl-gather gates, update creg, stage h to LDS
            const int base = lane & 48;
#pragma unroll
            for (int t = 0; t < 2; ++t) {
#pragma unroll
                for (int r = 0; r < 4; ++r) {
                    float vi, vf, vg, vo;
                    if constexpr (NCOLS == 32) {
                        vi = __shfl(acc[t][0][r], base + jj, 64);
                        vf = __shfl(acc[t][0][r], base + 8 + jj, 64);
                        vg = __shfl(acc[t][1][r], base + jj, 64);
                        vo = __shfl(acc[t][1][r], base + 8 + jj, 64);
                    } else {
                        vi = __shfl(acc[t][0][r], base + jj, 64);
                        vf = __shfl(acc[t][0][r], base + 4 + jj, 64);
                        vg = __shfl(acc[t][0][r], base + 8 + jj, 64);
                        vo = __shfl(acc[t][0][r], base + 12 + jj, 64);
                    }
                    bool cond; int slot;
                    if constexpr (NCOLS == 32) {
                        cond = (((lane >> 3) & 1) == (r & 1));
                        slot = t * 2 + (r >> 1);
                    } else {
                        cond = (((lane >> 2) & 3) == r);
                        slot = t;
                    }
                    if (cond) {
                        float cv = creg[slot];
                        float cn = sigmoidf_(vf + bias.y) * cv
                                 + sigmoidf_(vi + bias.x) * tanhf(vg + bias.z);
                        creg[slot] = cn;
                        float hn = sigmoidf_(vo + bias.w) * tanhf(cn);
                        hst[wv][t * 16 + quad * 4 + r][jj] = (bf16)hn;
                    }
                }
            }
            __syncthreads();
            // vectorized 8B relaxed-agent atomic stores (LLC write-through)
            if (lane < 32 * GPR) {
                int row_l = lane / GPR, cg = lane - row_l * GPR;
                ull v = *(const ull*)&hst[wv][row_l][cg * 4];
                __hip_atomic_store((ull*)(hw + (size_t)(wv * 32 + row_l) * H_ + n0h + cg * 4),
                                   v, __ATOMIC_RELAXED, __HIP_MEMORY_SCOPE_AGENT);
            }
        }

        // ---- flat epoch barrier: own-tag store + wave-0 sweep of all tags ----
        asm volatile("s_waitcnt vmcnt(0)" ::: "memory");
        __syncthreads();
        const unsigned etag = (unsigned)(e + 1);
        if (tid == 0)
            __hip_atomic_store(cnt + bid, etag,
                               __ATOMIC_RELAXED, __HIP_MEMORY_SCOPE_AGENT);
        if (tid < 64) {
            for (;;) {
                bool ok = true;
                for (int j = tid; j < nblk; j += 64)
                    ok &= (__hip_atomic_load(cnt + j, __ATOMIC_RELAXED,
                                             __HIP_MEMORY_SCOPE_AGENT) >= etag);
                if (__all(ok)) break;
                __builtin_amdgcn_s_sleep(2);
            }
            // acquire (cache inv) by wave 0 only: invalidates this CU's L1 + XCD L2
            __builtin_amdgcn_fence(__ATOMIC_ACQUIRE, "agent");
        }
        __syncthreads();
    }

    // ---- fused FC: out = h2^(256) @ Wfc^T + bfc ; h2^(256) is in h2b0 ----
    if (bid < B_) {
        const bf16* h2f = h2b0;
        for (int c = wv; c < C_; c += 4) {
            float a = 0.f;
            for (int k = lane; k < H_; k += 64)
                a += (float)h2f[(size_t)bid * H_ + k] * Wfc[(size_t)c * H_ + k];
#pragma unroll
            for (int off = 32; off; off >>= 1) a += __shfl_down(a, off, 64);
            if (lane == 0) out[bid * C_ + c] = a + bfc[c];
        }
    }
}

extern "C" void kernel_launch(void* const* d_in, const int* in_sizes, int n_in,
                              void* d_out, int out_size, void* d_ws, size_t ws_size,
                              hipStream_t stream)
{
    const float* x    = (const float*)d_in[0];
    const float* h1in = (const float*)d_in[1];
    const float* c1in = (const float*)d_in[2];
    const float* h2in = (const float*)d_in[3];
    const float* c2in = (const float*)d_in[4];
    const float* Wih1 = (const float*)d_in[5];
    const float* Whh1 = (const float*)d_in[6];
    const float* bih1 = (const float*)d_in[7];
    const float* bhh1 = (const float*)d_in[8];
    const float* Wih2 = (const float*)d_in[9];
    const float* Whh2 = (const float*)d_in[10];
    const float* bih2 = (const float*)d_in[11];
    const float* bhh2 = (const float*)d_in[12];
    const float* Wfc  = (const float*)d_in[13];
    const float* bfc  = (const float*)d_in[14];
    float* out = (float*)d_out;

    // ws carve (~11.5 MB)
    char* p = (char*)d_ws;
    bf16* xb = (bf16*)p;    p += (size_t)T_ * B_ * KX_ * 2;
    bf16* h1b0 = (bf16*)p;  p += (size_t)B_ * H_ * 2;
    bf16* h1b1 = (bf16*)p;  p += (size_t)B_ * H_ * 2;
    bf16* h2b0 = (bf16*)p;  p += (size_t)B_ * H_ * 2;
    bf16* h2b1 = (bf16*)p;  p += (size_t)B_ * H_ * 2;
    unsigned* cnt = (unsigned*)p;       // nblk u32 tags (4KB region zeroed)

    const size_t citems = (size_t)T_ * B_ * KX_ + 2 * (size_t)B_ * H_ + NLINES * CSTRIDE;
    convert_all<<<(int)((citems + 255) / 256), 256, 0, stream>>>(
        x, h1in, h2in, xb, h1b0, h2b0, cnt);

    int nblk32 = 256, nblk16 = 512;
    void* args32[] = { &xb, &h1b0, &h1b1, &h2b0, &h2b1, (void*)&c1in, (void*)&c2in,
                       (void*)&Wih1, (void*)&Whh1, (void*)&bih1, (void*)&bhh1,
                       (void*)&Wih2, (void*)&Whh2, (void*)&bih2, (void*)&bhh2,
                       (void*)&Wfc, (void*)&bfc, &out, &cnt, &nblk32 };
    void* args16[] = { &xb, &h1b0, &h1b1, &h2b0, &h2b1, (void*)&c1in, (void*)&c2in,
                       (void*)&Wih1, (void*)&Whh1, (void*)&bih1, (void*)&bhh1,
                       (void*)&Wih2, (void*)&Whh2, (void*)&bih2, (void*)&bhh2,
                       (void*)&Wfc, (void*)&bfc, &out, &cnt, &nblk16 };

    (void)hipFuncSetAttribute((const void*)rnn_persistent<32>,
                              hipFuncAttributeMaxDynamicSharedMemorySize, 131072);
    hipError_t err = hipLaunchCooperativeKernel((const void*)rnn_persistent<32>,
                                                dim3(256), dim3(256), args32,
                                                131072u, stream);
    if (err != hipSuccess) {
        (void)hipGetLastError();
        (void)hipFuncSetAttribute((const void*)rnn_persistent<16>,
                                  hipFuncAttributeMaxDynamicSharedMemorySize, 65536);
        (void)hipLaunchCooperativeKernel((const void*)rnn_persistent<16>,
                                         dim3(512), dim3(256), args16,
                                         65536u, stream);
    }
}

// Round 3
// 5221.629 us; speedup vs baseline: 1.1779x; 1.1779x over previous
//
#include <hip/hip_runtime.h>
#include <math.h>

// stacked_rnn R9: 8-wave blocks (512 threads) for 2x memory-level parallelism.
// R7 (flat barrier) regressed; R8 (asm-pinned load batch) broke numerics ->
// both reverted. Base protocol is R6 verbatim: relaxed-atomic h stores +
// vmcnt(0) flush + two-level aggregator barrier + wave-0 agent-acquire fence.
// R9's single structural change: each block runs 8 waves; each wave owns 16
// A-rows (a0 only, no a1). Same per-CU load/MFMA counts, but 2x independent
// wave contexts -> 2x loads in flight to hide post-invalidate L2-cold latency,
// lower per-wave VGPR pressure (deeper natural pipelining), halved per-wave
// epilogue chain. Proven R6 4-wave kernel kept verbatim as launch fallback.

typedef __bf16 bf16;
typedef __bf16 bf16x8 __attribute__((ext_vector_type(8)));
typedef float floatx4 __attribute__((ext_vector_type(4)));
typedef unsigned long long ull;

#define B_   128
#define T_   256
#define H_   1024
#define I_   150
#define KX_  160
#define C_   60
#define K1LDS 1280   // layer-1 LDS row width in elems
#define K2LDS 2048   // layer-2 LDS row width
#define NLINES 16    // counter lines
#define CSTRIDE 64   // uints between lines (256B)
#define NCOLS 32     // h-cols*4gates per block tile width
#define NHC  8       // h-cols per block (NCOLS/4)
#define NT   2       // N-tiles of 16

template<int N> struct IC { static constexpr int value = N; };

__device__ __forceinline__ float sigmoidf_(float x) { return 1.f / (1.f + expf(-x)); }

// ---------------- conversion / init kernel ----------------
__global__ __launch_bounds__(256)
void convert_all(const float* __restrict__ x,
                 const float* __restrict__ h1in, const float* __restrict__ h2in,
                 bf16* __restrict__ xb, bf16* __restrict__ h1b0, bf16* __restrict__ h2b0,
                 unsigned* __restrict__ cnt)
{
    const size_t nXB = (size_t)T_ * B_ * KX_;   // 5242880
    const size_t nHC = (size_t)B_ * H_;         // 131072
    size_t idx = (size_t)blockIdx.x * 256 + threadIdx.x;

    if (idx < nXB) {                            // x [B][T][150] -> xb [T][B][160]
        size_t t = idx / (B_ * KX_);
        size_t r = idx - t * (B_ * KX_);
        size_t b = r / KX_, k = r - b * KX_;
        xb[idx] = (k < I_) ? (bf16)x[(b * T_ + t) * I_ + k] : (bf16)0.f;
        return;
    }
    idx -= nXB;
    if (idx < nHC) { h1b0[idx] = (bf16)h1in[idx]; return; }
    idx -= nHC;
    if (idx < nHC) { h2b0[idx] = (bf16)h2in[idx]; return; }
    idx -= nHC;
    if (idx < NLINES * CSTRIDE) cnt[idx] = 0u;
}

// ---- shared device helper: stage weights fp32->bf16 into swizzled LDS ----
template<int NTHREADS>
__device__ __forceinline__ void stage_weights(
    bf16* lds, int tid, int layer, int n0h, int KLDS,
    const float* Wih1, const float* Whh1, const float* Wih2, const float* Whh2)
{
    const int cpr = KLDS >> 3;              // 16B chunks per row
    const int total = NCOLS * cpr;
    for (int ci = tid; ci < total; ci += NTHREADS) {
        int r = ci / cpr, c = ci - r * cpr;
        int g = r / NHC, j = r - g * NHC;
        int grow = (g << 10) + n0h + j;
        int k0 = c << 3;
        float v[8];
#pragma unroll
        for (int u = 0; u < 8; ++u) {
            int k = k0 + u;
            if (layer == 0)
                v[u] = (k < I_) ? Wih1[(size_t)grow * I_ + k]
                     : (k < KX_) ? 0.f
                     : (k < KX_ + H_) ? Whh1[(size_t)grow * H_ + (k - KX_)] : 0.f;
            else
                v[u] = (k < H_) ? Wih2[(size_t)grow * H_ + k]
                                : Whh2[(size_t)grow * H_ + (k - H_)];
        }
        int cs = (c & ~15) | ((c ^ r) & 15);      // XOR swizzle
        bf16* dst = lds + (size_t)r * KLDS + (cs << 3);
#pragma unroll
        for (int u = 0; u < 8; ++u) dst[u] = (bf16)v[u];
    }
}

// ================= R9 primary: 8-wave (512-thread) persistent kernel ========
// 256 blocks. layer = (bid>>3)&1, slice = (bid&7)|((bid>>4)<<3).
// Wave wv owns A-rows [wv*16, wv*16+16). cnt lines 0..7: arrival counters by
// (bid&7); line 8: epoch broadcast flag. Protocol identical to R6.
__global__ __launch_bounds__(512, 2)
void rnn_persistent8(const bf16* __restrict__ xb,
                     bf16* __restrict__ h1b0, bf16* __restrict__ h1b1,
                     bf16* __restrict__ h2b0, bf16* __restrict__ h2b1,
                     const float* __restrict__ c1in, const float* __restrict__ c2in,
                     const float* __restrict__ Wih1, const float* __restrict__ Whh1,
                     const float* __restrict__ bih1, const float* __restrict__ bhh1,
                     const float* __restrict__ Wih2, const float* __restrict__ Whh2,
                     const float* __restrict__ bih2, const float* __restrict__ bhh2,
                     const float* __restrict__ Wfc, const float* __restrict__ bfc,
                     float* __restrict__ out, unsigned* __restrict__ cnt, int nblk)
{
    extern __shared__ bf16 lds[];
    __shared__ __align__(16) bf16 hst[8][16][NHC];   // epilogue staging

    const int tid   = threadIdx.x;
    const int bid   = blockIdx.x;
    const int layer = (bid >> 3) & 1;
    const int slice = (bid & 7) | ((bid >> 4) << 3);
    const int n0h   = slice * NHC;
    const int KLDS  = layer ? K2LDS : K1LDS;
    const int arr_per_line = nblk >> 3;

    stage_weights<512>(lds, tid, layer, n0h, KLDS, Wih1, Whh1, Wih2, Whh2);
    __syncthreads();

    const int lane = tid & 63;
    const int wv   = tid >> 6;          // 0..7
    const int jj   = lane & (NHC - 1);
    const int quad = lane >> 4;

    float4 bias;
    {
        const float* bi = layer ? bih2 : bih1;
        const float* bh = layer ? bhh2 : bhh1;
        int col = n0h + jj;
        bias.x = bi[col] + bh[col];
        bias.y = bi[col + H_] + bh[col + H_];
        bias.z = bi[col + 2 * H_] + bh[col + 2 * H_];
        bias.w = bi[col + 3 * H_] + bh[col + 3 * H_];
    }

    float creg[2];
    {
        const float* cin = layer ? c2in : c1in;
        int dup = (lane >> 3) & 1;
#pragma unroll
        for (int rp = 0; rp < 2; ++rp) {
            int row = wv * 16 + quad * 4 + rp * 2 + dup;
            creg[rp] = cin[(size_t)row * H_ + n0h + jj];
        }
    }

    floatx4 acc[NT];

    // K-segment: wave owns 16 A-rows; 1 load + NT MFMAs per k-chunk.
    auto seg = [&](const bf16* A, int ldA, auto nksC, int ksBase) {
        constexpr int NKS = decltype(nksC)::value;
        constexpr int CH  = NKS < 16 ? NKS : 16;
        const int arow = wv * 16 + (lane & 15);
        const bf16* a0 = A + (size_t)arow * ldA + quad * 8;
        for (int blk = 0; blk < NKS; blk += CH) {
            bf16x8 a0r[CH];
#pragma unroll
            for (int i = 0; i < CH; ++i)
                a0r[i] = *(const bf16x8*)(a0 + (blk + i) * 32);
#pragma unroll
            for (int i = 0; i < CH; ++i) {
                int c = (ksBase + blk + i) * 4 + quad;
#pragma unroll
                for (int t = 0; t < NT; ++t) {
                    int r = t * 16 + (lane & 15);
                    int cs = (c & ~15) | ((c ^ r) & 15);
                    bf16x8 bfr = *(const bf16x8*)(lds + (size_t)r * KLDS + (cs << 3));
                    acc[t] = __builtin_amdgcn_mfma_f32_16x16x32_bf16(a0r[i], bfr, acc[t], 0, 0, 0);
                }
            }
        }
    };

    for (int e = 0; e <= T_; ++e) {
        const bool active = layer == 0 ? (e < T_) : (e >= 1);
        if (active) {
#pragma unroll
            for (int t = 0; t < NT; ++t) acc[t] = (floatx4){0.f, 0.f, 0.f, 0.f};

            const bf16* h1r = (e & 1) ? h1b1 : h1b0;         // h1^(e)
            if (layer == 0) {
                const bf16* xt = xb + (size_t)e * B_ * KX_;
                seg(xt, KX_, IC<5>{}, 0);
                seg(h1r, H_, IC<32>{}, 5);
            } else {
                const bf16* h2r = (e & 1) ? h2b0 : h2b1;     // h2^(e-1)
                seg(h1r, H_, IC<32>{}, 0);
                seg(h2r, H_, IC<32>{}, 32);
            }
            bf16* hw = (layer == 0) ? ((e & 1) ? h1b0 : h1b1)   // h1^(e+1)
                                    : ((e & 1) ? h2b1 : h2b0);  // h2^(e)

            // epilogue: shfl-gather gates, update creg, stage h to LDS.
            // acc[0] covers output cols 0..15 (gates i,f), acc[1] cols 16..31
            // (gates g,o). C-row = quad*4+r maps to A-row wv*16+quad*4+r.
            const int base = lane & 48;
#pragma unroll
            for (int r = 0; r < 4; ++r) {
                float vi = __shfl(acc[0][r], base + jj, 64);
                float vf = __shfl(acc[0][r], base + 8 + jj, 64);
                float vg = __shfl(acc[1][r], base + jj, 64);
                float vo = __shfl(acc[1][r], base + 8 + jj, 64);
                bool cond = (((lane >> 3) & 1) == (r & 1));
                int slot = r >> 1;
                if (cond) {
                    float cv = creg[slot];
                    float cn = sigmoidf_(vf + bias.y) * cv
                             + sigmoidf_(vi + bias.x) * tanhf(vg + bias.z);
                    creg[slot] = cn;
                    float hn = sigmoidf_(vo + bias.w) * tanhf(cn);
                    hst[wv][quad * 4 + r][jj] = (bf16)hn;
                }
            }
            __syncthreads();
            // vectorized 8B relaxed-agent atomic stores (LLC write-through)
            if (lane < 32) {
                int row_l = lane >> 1, cg = lane & 1;
                ull v = *(const ull*)&hst[wv][row_l][cg * 4];
                __hip_atomic_store((ull*)(hw + (size_t)(wv * 16 + row_l) * H_ + n0h + cg * 4),
                                   v, __ATOMIC_RELAXED, __HIP_MEMORY_SCOPE_AGENT);
            }
        }

        // ---- two-level barrier: RMW lines (0..7) + broadcast flag line (8) ----
        asm volatile("s_waitcnt vmcnt(0)" ::: "memory");
        __syncthreads();
        const unsigned etag = (unsigned)(e + 1);
        if (bid == 0) {
            if (tid == 0)
                __hip_atomic_fetch_add(cnt, 1u, __ATOMIC_RELAXED, __HIP_MEMORY_SCOPE_AGENT);
            if (tid < 8) {
                const unsigned tgt = etag * (unsigned)arr_per_line;
                const unsigned* cp = cnt + tid * CSTRIDE;
                while (__hip_atomic_load(cp, __ATOMIC_RELAXED, __HIP_MEMORY_SCOPE_AGENT) < tgt)
                    __builtin_amdgcn_s_sleep(1);
            }
            if (tid == 0)
                __hip_atomic_store(cnt + 8 * CSTRIDE, etag,
                                   __ATOMIC_RELAXED, __HIP_MEMORY_SCOPE_AGENT);
        } else {
            if (tid == 0) {
                __hip_atomic_fetch_add(cnt + (bid & 7) * CSTRIDE, 1u,
                                       __ATOMIC_RELAXED, __HIP_MEMORY_SCOPE_AGENT);
                const unsigned* fp = cnt + 8 * CSTRIDE;
                while (__hip_atomic_load(fp, __ATOMIC_RELAXED, __HIP_MEMORY_SCOPE_AGENT) < etag)
                    __builtin_amdgcn_s_sleep(1);
            }
        }
        __syncthreads();
        // acquire (cache inv) by wave 0 only: invalidates this CU's L1 + XCD L2
        if (tid < 64)
            __builtin_amdgcn_fence(__ATOMIC_ACQUIRE, "agent");
        __syncthreads();
    }

    // ---- fused FC: out = h2^(256) @ Wfc^T + bfc ; h2^(256) is in h2b0 ----
    if (bid < B_) {
        const bf16* h2f = h2b0;
        for (int c = wv; c < C_; c += 8) {
            float a = 0.f;
            for (int k = lane; k < H_; k += 64)
                a += (float)h2f[(size_t)bid * H_ + k] * Wfc[(size_t)c * H_ + k];
#pragma unroll
            for (int off = 32; off; off >>= 1) a += __shfl_down(a, off, 64);
            if (lane == 0) out[bid * C_ + c] = a + bfc[c];
        }
    }
}

// ================= fallback: proven R6 4-wave (256-thread) kernel ===========
__global__ __launch_bounds__(256, 1)
void rnn_persistent4(const bf16* __restrict__ xb,
                     bf16* __restrict__ h1b0, bf16* __restrict__ h1b1,
                     bf16* __restrict__ h2b0, bf16* __restrict__ h2b1,
                     const float* __restrict__ c1in, const float* __restrict__ c2in,
                     const float* __restrict__ Wih1, const float* __restrict__ Whh1,
                     const float* __restrict__ bih1, const float* __restrict__ bhh1,
                     const float* __restrict__ Wih2, const float* __restrict__ Whh2,
                     const float* __restrict__ bih2, const float* __restrict__ bhh2,
                     const float* __restrict__ Wfc, const float* __restrict__ bfc,
                     float* __restrict__ out, unsigned* __restrict__ cnt, int nblk)
{
    extern __shared__ bf16 lds[];
    __shared__ __align__(16) bf16 hst[4][32][NHC];

    const int tid   = threadIdx.x;
    const int bid   = blockIdx.x;
    const int layer = (bid >> 3) & 1;
    const int slice = (bid & 7) | ((bid >> 4) << 3);
    const int n0h   = slice * NHC;
    const int KLDS  = layer ? K2LDS : K1LDS;
    const int arr_per_line = nblk >> 3;

    stage_weights<256>(lds, tid, layer, n0h, KLDS, Wih1, Whh1, Wih2, Whh2);
    __syncthreads();

    const int lane = tid & 63;
    const int wv   = tid >> 6;
    const int jj   = lane & (NHC - 1);
    const int quad = lane >> 4;

    float4 bias;
    {
        const float* bi = layer ? bih2 : bih1;
        const float* bh = layer ? bhh2 : bhh1;
        int col = n0h + jj;
        bias.x = bi[col] + bh[col];
        bias.y = bi[col + H_] + bh[col + H_];
        bias.z = bi[col + 2 * H_] + bh[col + 2 * H_];
        bias.w = bi[col + 3 * H_] + bh[col + 3 * H_];
    }

    float creg[4];
    {
        const float* cin = layer ? c2in : c1in;
        int dup = (lane >> 3) & 1;
#pragma unroll
        for (int t = 0; t < 2; ++t)
#pragma unroll
            for (int rp = 0; rp < 2; ++rp) {
                int r = rp * 2 + dup;
                int row = wv * 32 + t * 16 + quad * 4 + r;
                creg[t * 2 + rp] = cin[(size_t)row * H_ + n0h + jj];
            }
    }

    floatx4 acc[2][NT];

    auto seg = [&](const bf16* A, int ldA, auto nksC, int ksBase) {
        constexpr int NKS = decltype(nksC)::value;
        constexpr int CH  = NKS < 16 ? NKS : 16;
        const int arow = wv * 32 + (lane & 15);
        const bf16* a0 = A + (size_t)arow * ldA + quad * 8;
        const bf16* a1 = a0 + 16 * ldA;
        for (int blk = 0; blk < NKS; blk += CH) {
            bf16x8 a0r[CH], a1r[CH];
#pragma unroll
            for (int i = 0; i < CH; ++i) {
                a0r[i] = *(const bf16x8*)(a0 + (blk + i) * 32);
                a1r[i] = *(const bf16x8*)(a1 + (blk + i) * 32);
            }
#pragma unroll
            for (int i = 0; i < CH; ++i) {
                int c = (ksBase + blk + i) * 4 + quad;
#pragma unroll
                for (int t = 0; t < NT; ++t) {
                    int r = t * 16 + (lane & 15);
                    int cs = (c & ~15) | ((c ^ r) & 15);
                    bf16x8 bfr = *(const bf16x8*)(lds + (size_t)r * KLDS + (cs << 3));
                    acc[0][t] = __builtin_amdgcn_mfma_f32_16x16x32_bf16(a0r[i], bfr, acc[0][t], 0, 0, 0);
                    acc[1][t] = __builtin_amdgcn_mfma_f32_16x16x32_bf16(a1r[i], bfr, acc[1][t], 0, 0, 0);
                }
            }
        }
    };

    for (int e = 0; e <= T_; ++e) {
        const bool active = layer == 0 ? (e < T_) : (e >= 1);
        if (active) {
#pragma unroll
            for (int t = 0; t < 2; ++t)
#pragma unroll
                for (int u = 0; u < NT; ++u) acc[t][u] = (floatx4){0.f, 0.f, 0.f, 0.f};

            const bf16* h1r = (e & 1) ? h1b1 : h1b0;
            if (layer == 0) {
                const bf16* xt = xb + (size_t)e * B_ * KX_;
                seg(xt, KX_, IC<5>{}, 0);
                seg(h1r, H_, IC<32>{}, 5);
            } else {
                const bf16* h2r = (e & 1) ? h2b0 : h2b1;
                seg(h1r, H_, IC<32>{}, 0);
                seg(h2r, H_, IC<32>{}, 32);
            }
            bf16* hw = (layer == 0) ? ((e & 1) ? h1b0 : h1b1)
                                    : ((e & 1) ? h2b1 : h2b0);

            const int base = lane & 48;
#pragma unroll
            for (int t = 0; t < 2; ++t) {
#pragma unroll
                for (int r = 0; r < 4; ++r) {
                    float vi = __shfl(acc[t][0][r], base + jj, 64);
                    float vf = __shfl(acc[t][0][r], base + 8 + jj, 64);
                    float vg = __shfl(acc[t][1][r], base + jj, 64);
                    float vo = __shfl(acc[t][1][r], base + 8 + jj, 64);
                    bool cond = (((lane >> 3) & 1) == (r & 1));
                    int slot = t * 2 + (r >> 1);
                    if (cond) {
                        float cv = creg[slot];
                        float cn = sigmoidf_(vf + bias.y) * cv
                                 + sigmoidf_(vi + bias.x) * tanhf(vg + bias.z);
                        creg[slot] = cn;
                        float hn = sigmoidf_(vo + bias.w) * tanhf(cn);
                        hst[wv][t * 16 + quad * 4 + r][jj] = (bf16)hn;
                    }
                }
            }
            __syncthreads();
            if (lane < 64) {
                int row_l = lane >> 1, cg = lane & 1;
                ull v = *(const ull*)&hst[wv][row_l][cg * 4];
                __hip_atomic_store((ull*)(hw + (size_t)(wv * 32 + row_l) * H_ + n0h + cg * 4),
                                   v, __ATOMIC_RELAXED, __HIP_MEMORY_SCOPE_AGENT);
            }
        }

        asm volatile("s_waitcnt vmcnt(0)" ::: "memory");
        __syncthreads();
        const unsigned etag = (unsigned)(e + 1);
        if (bid == 0) {
            if (tid == 0)
                __hip_atomic_fetch_add(cnt, 1u, __ATOMIC_RELAXED, __HIP_MEMORY_SCOPE_AGENT);
            if (tid < 8) {
                const unsigned tgt = etag * (unsigned)arr_per_line;
                const unsigned* cp = cnt + tid * CSTRIDE;
                while (__hip_atomic_load(cp, __ATOMIC_RELAXED, __HIP_MEMORY_SCOPE_AGENT) < tgt)
                    __builtin_amdgcn_s_sleep(1);
            }
            if (tid == 0)
                __hip_atomic_store(cnt + 8 * CSTRIDE, etag,
                                   __ATOMIC_RELAXED, __HIP_MEMORY_SCOPE_AGENT);
        } else {
            if (tid == 0) {
                __hip_atomic_fetch_add(cnt + (bid & 7) * CSTRIDE, 1u,
                                       __ATOMIC_RELAXED, __HIP_MEMORY_SCOPE_AGENT);
                const unsigned* fp = cnt + 8 * CSTRIDE;
                while (__hip_atomic_load(fp, __ATOMIC_RELAXED, __HIP_MEMORY_SCOPE_AGENT) < etag)
                    __builtin_amdgcn_s_sleep(1);
            }
        }
        __syncthreads();
        if (tid < 64)
            __builtin_amdgcn_fence(__ATOMIC_ACQUIRE, "agent");
        __syncthreads();
    }

    if (bid < B_) {
        const bf16* h2f = h2b0;
        for (int c = wv; c < C_; c += 4) {
            float a = 0.f;
            for (int k = lane; k < H_; k += 64)
                a += (float)h2f[(size_t)bid * H_ + k] * Wfc[(size_t)c * H_ + k];
#pragma unroll
            for (int off = 32; off; off >>= 1) a += __shfl_down(a, off, 64);
            if (lane == 0) out[bid * C_ + c] = a + bfc[c];
        }
    }
}

extern "C" void kernel_launch(void* const* d_in, const int* in_sizes, int n_in,
                              void* d_out, int out_size, void* d_ws, size_t ws_size,
                              hipStream_t stream)
{
    const float* x    = (const float*)d_in[0];
    const float* h1in = (const float*)d_in[1];
    const float* c1in = (const float*)d_in[2];
    const float* h2in = (const float*)d_in[3];
    const float* c2in = (const float*)d_in[4];
    const float* Wih1 = (const float*)d_in[5];
    const float* Whh1 = (const float*)d_in[6];
    const float* bih1 = (const float*)d_in[7];
    const float* bhh1 = (const float*)d_in[8];
    const float* Wih2 = (const float*)d_in[9];
    const float* Whh2 = (const float*)d_in[10];
    const float* bih2 = (const float*)d_in[11];
    const float* bhh2 = (const float*)d_in[12];
    const float* Wfc  = (const float*)d_in[13];
    const float* bfc  = (const float*)d_in[14];
    float* out = (float*)d_out;

    // ws carve (~11.5 MB)
    char* p = (char*)d_ws;
    bf16* xb = (bf16*)p;    p += (size_t)T_ * B_ * KX_ * 2;
    bf16* h1b0 = (bf16*)p;  p += (size_t)B_ * H_ * 2;
    bf16* h1b1 = (bf16*)p;  p += (size_t)B_ * H_ * 2;
    bf16* h2b0 = (bf16*)p;  p += (size_t)B_ * H_ * 2;
    bf16* h2b1 = (bf16*)p;  p += (size_t)B_ * H_ * 2;
    unsigned* cnt = (unsigned*)p;       // 16 lines x 256B

    const size_t citems = (size_t)T_ * B_ * KX_ + 2 * (size_t)B_ * H_ + NLINES * CSTRIDE;
    convert_all<<<(int)((citems + 255) / 256), 256, 0, stream>>>(
        x, h1in, h2in, xb, h1b0, h2b0, cnt);

    int nblk = 256;
    void* args[] = { &xb, &h1b0, &h1b1, &h2b0, &h2b1, (void*)&c1in, (void*)&c2in,
                     (void*)&Wih1, (void*)&Whh1, (void*)&bih1, (void*)&bhh1,
                     (void*)&Wih2, (void*)&Whh2, (void*)&bih2, (void*)&bhh2,
                     (void*)&Wfc, (void*)&bfc, &out, &cnt, &nblk };

    (void)hipFuncSetAttribute((const void*)rnn_persistent8,
                              hipFuncAttributeMaxDynamicSharedMemorySize, 131072);
    hipError_t err = hipLaunchCooperativeKernel((const void*)rnn_persistent8,
                                                dim3(256), dim3(512), args,
                                                131072u, stream);
    if (err != hipSuccess) {
        (void)hipGetLastError();
        (void)hipFuncSetAttribute((const void*)rnn_persistent4,
                                  hipFuncAttributeMaxDynamicSharedMemorySize, 131072);
        (void)hipLaunchCooperativeKernel((const void*)rnn_persistent4,
                                         dim3(256), dim3(256), args,
                                         131072u, stream);
    }
}

// Round 4
// 5140.159 us; speedup vs baseline: 1.1966x; 1.0158x over previous
//
#include <hip/hip_runtime.h>
#include <math.h>

// stacked_rnn R10: R9 (8-wave, proven) + sched_barrier(0) load-batch pin.
// R9 won (5591->5222) but VGPR=76 shows the CH=16 register batch in seg() is
// still collapsed by the compiler (needs 64 VGPRs of batch) -> A-stream runs
// ~2-4 loads deep, latency-bound post-invalidate. R8's asm-"memory" pin broke
// numerics (unexplained -> mechanism banned). R10 uses the scheduler-only
// tool: __builtin_amdgcn_sched_barrier(0) between load-issue and consume
// loops. SCHED_BARRIER is a machine-scheduler fence with no memory-model
// semantics -> cannot interact with the relaxed-atomic protocol. Engagement
// check: VGPR must rise to ~140-180. Everything else byte-identical to R9.

typedef __bf16 bf16;
typedef __bf16 bf16x8 __attribute__((ext_vector_type(8)));
typedef float floatx4 __attribute__((ext_vector_type(4)));
typedef unsigned long long ull;

#define B_   128
#define T_   256
#define H_   1024
#define I_   150
#define KX_  160
#define C_   60
#define K1LDS 1280   // layer-1 LDS row width in elems
#define K2LDS 2048   // layer-2 LDS row width
#define NLINES 16    // counter lines
#define CSTRIDE 64   // uints between lines (256B)
#define NCOLS 32     // h-cols*4gates per block tile width
#define NHC  8       // h-cols per block (NCOLS/4)
#define NT   2       // N-tiles of 16

template<int N> struct IC { static constexpr int value = N; };

__device__ __forceinline__ float sigmoidf_(float x) { return 1.f / (1.f + expf(-x)); }

// ---------------- conversion / init kernel ----------------
__global__ __launch_bounds__(256)
void convert_all(const float* __restrict__ x,
                 const float* __restrict__ h1in, const float* __restrict__ h2in,
                 bf16* __restrict__ xb, bf16* __restrict__ h1b0, bf16* __restrict__ h2b0,
                 unsigned* __restrict__ cnt)
{
    const size_t nXB = (size_t)T_ * B_ * KX_;   // 5242880
    const size_t nHC = (size_t)B_ * H_;         // 131072
    size_t idx = (size_t)blockIdx.x * 256 + threadIdx.x;

    if (idx < nXB) {                            // x [B][T][150] -> xb [T][B][160]
        size_t t = idx / (B_ * KX_);
        size_t r = idx - t * (B_ * KX_);
        size_t b = r / KX_, k = r - b * KX_;
        xb[idx] = (k < I_) ? (bf16)x[(b * T_ + t) * I_ + k] : (bf16)0.f;
        return;
    }
    idx -= nXB;
    if (idx < nHC) { h1b0[idx] = (bf16)h1in[idx]; return; }
    idx -= nHC;
    if (idx < nHC) { h2b0[idx] = (bf16)h2in[idx]; return; }
    idx -= nHC;
    if (idx < NLINES * CSTRIDE) cnt[idx] = 0u;
}

// ---- shared device helper: stage weights fp32->bf16 into swizzled LDS ----
template<int NTHREADS>
__device__ __forceinline__ void stage_weights(
    bf16* lds, int tid, int layer, int n0h, int KLDS,
    const float* Wih1, const float* Whh1, const float* Wih2, const float* Whh2)
{
    const int cpr = KLDS >> 3;              // 16B chunks per row
    const int total = NCOLS * cpr;
    for (int ci = tid; ci < total; ci += NTHREADS) {
        int r = ci / cpr, c = ci - r * cpr;
        int g = r / NHC, j = r - g * NHC;
        int grow = (g << 10) + n0h + j;
        int k0 = c << 3;
        float v[8];
#pragma unroll
        for (int u = 0; u < 8; ++u) {
            int k = k0 + u;
            if (layer == 0)
                v[u] = (k < I_) ? Wih1[(size_t)grow * I_ + k]
                     : (k < KX_) ? 0.f
                     : (k < KX_ + H_) ? Whh1[(size_t)grow * H_ + (k - KX_)] : 0.f;
            else
                v[u] = (k < H_) ? Wih2[(size_t)grow * H_ + k]
                                : Whh2[(size_t)grow * H_ + (k - H_)];
        }
        int cs = (c & ~15) | ((c ^ r) & 15);      // XOR swizzle
        bf16* dst = lds + (size_t)r * KLDS + (cs << 3);
#pragma unroll
        for (int u = 0; u < 8; ++u) dst[u] = (bf16)v[u];
    }
}

// ================= R10 primary: 8-wave (512-thread) persistent kernel =======
// 256 blocks. layer = (bid>>3)&1, slice = (bid&7)|((bid>>4)<<3).
// Wave wv owns A-rows [wv*16, wv*16+16). cnt lines 0..7: arrival counters by
// (bid&7); line 8: epoch broadcast flag. Protocol identical to R6/R9.
__global__ __launch_bounds__(512, 2)
void rnn_persistent8(const bf16* __restrict__ xb,
                     bf16* __restrict__ h1b0, bf16* __restrict__ h1b1,
                     bf16* __restrict__ h2b0, bf16* __restrict__ h2b1,
                     const float* __restrict__ c1in, const float* __restrict__ c2in,
                     const float* __restrict__ Wih1, const float* __restrict__ Whh1,
                     const float* __restrict__ bih1, const float* __restrict__ bhh1,
                     const float* __restrict__ Wih2, const float* __restrict__ Whh2,
                     const float* __restrict__ bih2, const float* __restrict__ bhh2,
                     const float* __restrict__ Wfc, const float* __restrict__ bfc,
                     float* __restrict__ out, unsigned* __restrict__ cnt, int nblk)
{
    extern __shared__ bf16 lds[];
    __shared__ __align__(16) bf16 hst[8][16][NHC];   // epilogue staging

    const int tid   = threadIdx.x;
    const int bid   = blockIdx.x;
    const int layer = (bid >> 3) & 1;
    const int slice = (bid & 7) | ((bid >> 4) << 3);
    const int n0h   = slice * NHC;
    const int KLDS  = layer ? K2LDS : K1LDS;
    const int arr_per_line = nblk >> 3;

    stage_weights<512>(lds, tid, layer, n0h, KLDS, Wih1, Whh1, Wih2, Whh2);
    __syncthreads();

    const int lane = tid & 63;
    const int wv   = tid >> 6;          // 0..7
    const int jj   = lane & (NHC - 1);
    const int quad = lane >> 4;

    float4 bias;
    {
        const float* bi = layer ? bih2 : bih1;
        const float* bh = layer ? bhh2 : bhh1;
        int col = n0h + jj;
        bias.x = bi[col] + bh[col];
        bias.y = bi[col + H_] + bh[col + H_];
        bias.z = bi[col + 2 * H_] + bh[col + 2 * H_];
        bias.w = bi[col + 3 * H_] + bh[col + 3 * H_];
    }

    float creg[2];
    {
        const float* cin = layer ? c2in : c1in;
        int dup = (lane >> 3) & 1;
#pragma unroll
        for (int rp = 0; rp < 2; ++rp) {
            int row = wv * 16 + quad * 4 + rp * 2 + dup;
            creg[rp] = cin[(size_t)row * H_ + n0h + jj];
        }
    }

    floatx4 acc[NT];

    // K-segment: wave owns 16 A-rows; 1 load + NT MFMAs per k-chunk.
    // CH loads are issued first, then sched_barrier(0) pins them (machine-
    // scheduler only: no load may sink past it, no MFMA may hoist above it)
    // -> CH loads in flight hide post-invalidate LLC latency.
    auto seg = [&](const bf16* A, int ldA, auto nksC, int ksBase) {
        constexpr int NKS = decltype(nksC)::value;
        constexpr int CH  = NKS < 16 ? NKS : 16;
        const int arow = wv * 16 + (lane & 15);
        const bf16* a0 = A + (size_t)arow * ldA + quad * 8;
        for (int blk = 0; blk < NKS; blk += CH) {
            bf16x8 a0r[CH];
#pragma unroll
            for (int i = 0; i < CH; ++i)
                a0r[i] = *(const bf16x8*)(a0 + (blk + i) * 32);
            __builtin_amdgcn_sched_barrier(0);   // pin the batch (sched-only)
#pragma unroll
            for (int i = 0; i < CH; ++i) {
                int c = (ksBase + blk + i) * 4 + quad;
#pragma unroll
                for (int t = 0; t < NT; ++t) {
                    int r = t * 16 + (lane & 15);
                    int cs = (c & ~15) | ((c ^ r) & 15);
                    bf16x8 bfr = *(const bf16x8*)(lds + (size_t)r * KLDS + (cs << 3));
                    acc[t] = __builtin_amdgcn_mfma_f32_16x16x32_bf16(a0r[i], bfr, acc[t], 0, 0, 0);
                }
            }
        }
    };

    for (int e = 0; e <= T_; ++e) {
        const bool active = layer == 0 ? (e < T_) : (e >= 1);
        if (active) {
#pragma unroll
            for (int t = 0; t < NT; ++t) acc[t] = (floatx4){0.f, 0.f, 0.f, 0.f};

            const bf16* h1r = (e & 1) ? h1b1 : h1b0;         // h1^(e)
            if (layer == 0) {
                const bf16* xt = xb + (size_t)e * B_ * KX_;
                seg(xt, KX_, IC<5>{}, 0);
                seg(h1r, H_, IC<32>{}, 5);
            } else {
                const bf16* h2r = (e & 1) ? h2b0 : h2b1;     // h2^(e-1)
                seg(h1r, H_, IC<32>{}, 0);
                seg(h2r, H_, IC<32>{}, 32);
            }
            bf16* hw = (layer == 0) ? ((e & 1) ? h1b0 : h1b1)   // h1^(e+1)
                                    : ((e & 1) ? h2b1 : h2b0);  // h2^(e)

            // epilogue: shfl-gather gates, update creg, stage h to LDS.
            const int base = lane & 48;
#pragma unroll
            for (int r = 0; r < 4; ++r) {
                float vi = __shfl(acc[0][r], base + jj, 64);
                float vf = __shfl(acc[0][r], base + 8 + jj, 64);
                float vg = __shfl(acc[1][r], base + jj, 64);
                float vo = __shfl(acc[1][r], base + 8 + jj, 64);
                bool cond = (((lane >> 3) & 1) == (r & 1));
                int slot = r >> 1;
                if (cond) {
                    float cv = creg[slot];
                    float cn = sigmoidf_(vf + bias.y) * cv
                             + sigmoidf_(vi + bias.x) * tanhf(vg + bias.z);
                    creg[slot] = cn;
                    float hn = sigmoidf_(vo + bias.w) * tanhf(cn);
                    hst[wv][quad * 4 + r][jj] = (bf16)hn;
                }
            }
            __syncthreads();
            // vectorized 8B relaxed-agent atomic stores (LLC write-through)
            if (lane < 32) {
                int row_l = lane >> 1, cg = lane & 1;
                ull v = *(const ull*)&hst[wv][row_l][cg * 4];
                __hip_atomic_store((ull*)(hw + (size_t)(wv * 16 + row_l) * H_ + n0h + cg * 4),
                                   v, __ATOMIC_RELAXED, __HIP_MEMORY_SCOPE_AGENT);
            }
        }

        // ---- two-level barrier: RMW lines (0..7) + broadcast flag line (8) ----
        asm volatile("s_waitcnt vmcnt(0)" ::: "memory");
        __syncthreads();
        const unsigned etag = (unsigned)(e + 1);
        if (bid == 0) {
            if (tid == 0)
                __hip_atomic_fetch_add(cnt, 1u, __ATOMIC_RELAXED, __HIP_MEMORY_SCOPE_AGENT);
            if (tid < 8) {
                const unsigned tgt = etag * (unsigned)arr_per_line;
                const unsigned* cp = cnt + tid * CSTRIDE;
                while (__hip_atomic_load(cp, __ATOMIC_RELAXED, __HIP_MEMORY_SCOPE_AGENT) < tgt)
                    __builtin_amdgcn_s_sleep(1);
            }
            if (tid == 0)
                __hip_atomic_store(cnt + 8 * CSTRIDE, etag,
                                   __ATOMIC_RELAXED, __HIP_MEMORY_SCOPE_AGENT);
        } else {
            if (tid == 0) {
                __hip_atomic_fetch_add(cnt + (bid & 7) * CSTRIDE, 1u,
                                       __ATOMIC_RELAXED, __HIP_MEMORY_SCOPE_AGENT);
                const unsigned* fp = cnt + 8 * CSTRIDE;
                while (__hip_atomic_load(fp, __ATOMIC_RELAXED, __HIP_MEMORY_SCOPE_AGENT) < etag)
                    __builtin_amdgcn_s_sleep(1);
            }
        }
        __syncthreads();
        // acquire (cache inv) by wave 0 only: invalidates this CU's L1 + XCD L2
        if (tid < 64)
            __builtin_amdgcn_fence(__ATOMIC_ACQUIRE, "agent");
        __syncthreads();
    }

    // ---- fused FC: out = h2^(256) @ Wfc^T + bfc ; h2^(256) is in h2b0 ----
    if (bid < B_) {
        const bf16* h2f = h2b0;
        for (int c = wv; c < C_; c += 8) {
            float a = 0.f;
            for (int k = lane; k < H_; k += 64)
                a += (float)h2f[(size_t)bid * H_ + k] * Wfc[(size_t)c * H_ + k];
#pragma unroll
            for (int off = 32; off; off >>= 1) a += __shfl_down(a, off, 64);
            if (lane == 0) out[bid * C_ + c] = a + bfc[c];
        }
    }
}

// ================= fallback: proven R6 4-wave (256-thread) kernel ===========
__global__ __launch_bounds__(256, 1)
void rnn_persistent4(const bf16* __restrict__ xb,
                     bf16* __restrict__ h1b0, bf16* __restrict__ h1b1,
                     bf16* __restrict__ h2b0, bf16* __restrict__ h2b1,
                     const float* __restrict__ c1in, const float* __restrict__ c2in,
                     const float* __restrict__ Wih1, const float* __restrict__ Whh1,
                     const float* __restrict__ bih1, const float* __restrict__ bhh1,
                     const float* __restrict__ Wih2, const float* __restrict__ Whh2,
                     const float* __restrict__ bih2, const float* __restrict__ bhh2,
                     const float* __restrict__ Wfc, const float* __restrict__ bfc,
                     float* __restrict__ out, unsigned* __restrict__ cnt, int nblk)
{
    extern __shared__ bf16 lds[];
    __shared__ __align__(16) bf16 hst[4][32][NHC];

    const int tid   = threadIdx.x;
    const int bid   = blockIdx.x;
    const int layer = (bid >> 3) & 1;
    const int slice = (bid & 7) | ((bid >> 4) << 3);
    const int n0h   = slice * NHC;
    const int KLDS  = layer ? K2LDS : K1LDS;
    const int arr_per_line = nblk >> 3;

    stage_weights<256>(lds, tid, layer, n0h, KLDS, Wih1, Whh1, Wih2, Whh2);
    __syncthreads();

    const int lane = tid & 63;
    const int wv   = tid >> 6;
    const int jj   = lane & (NHC - 1);
    const int quad = lane >> 4;

    float4 bias;
    {
        const float* bi = layer ? bih2 : bih1;
        const float* bh = layer ? bhh2 : bhh1;
        int col = n0h + jj;
        bias.x = bi[col] + bh[col];
        bias.y = bi[col + H_] + bh[col + H_];
        bias.z = bi[col + 2 * H_] + bh[col + 2 * H_];
        bias.w = bi[col + 3 * H_] + bh[col + 3 * H_];
    }

    float creg[4];
    {
        const float* cin = layer ? c2in : c1in;
        int dup = (lane >> 3) & 1;
#pragma unroll
        for (int t = 0; t < 2; ++t)
#pragma unroll
            for (int rp = 0; rp < 2; ++rp) {
                int r = rp * 2 + dup;
                int row = wv * 32 + t * 16 + quad * 4 + r;
                creg[t * 2 + rp] = cin[(size_t)row * H_ + n0h + jj];
            }
    }

    floatx4 acc[2][NT];

    auto seg = [&](const bf16* A, int ldA, auto nksC, int ksBase) {
        constexpr int NKS = decltype(nksC)::value;
        constexpr int CH  = NKS < 16 ? NKS : 16;
        const int arow = wv * 32 + (lane & 15);
        const bf16* a0 = A + (size_t)arow * ldA + quad * 8;
        const bf16* a1 = a0 + 16 * ldA;
        for (int blk = 0; blk < NKS; blk += CH) {
            bf16x8 a0r[CH], a1r[CH];
#pragma unroll
            for (int i = 0; i < CH; ++i) {
                a0r[i] = *(const bf16x8*)(a0 + (blk + i) * 32);
                a1r[i] = *(const bf16x8*)(a1 + (blk + i) * 32);
            }
#pragma unroll
            for (int i = 0; i < CH; ++i) {
                int c = (ksBase + blk + i) * 4 + quad;
#pragma unroll
                for (int t = 0; t < NT; ++t) {
                    int r = t * 16 + (lane & 15);
                    int cs = (c & ~15) | ((c ^ r) & 15);
                    bf16x8 bfr = *(const bf16x8*)(lds + (size_t)r * KLDS + (cs << 3));
                    acc[0][t] = __builtin_amdgcn_mfma_f32_16x16x32_bf16(a0r[i], bfr, acc[0][t], 0, 0, 0);
                    acc[1][t] = __builtin_amdgcn_mfma_f32_16x16x32_bf16(a1r[i], bfr, acc[1][t], 0, 0, 0);
                }
            }
        }
    };

    for (int e = 0; e <= T_; ++e) {
        const bool active = layer == 0 ? (e < T_) : (e >= 1);
        if (active) {
#pragma unroll
            for (int t = 0; t < 2; ++t)
#pragma unroll
                for (int u = 0; u < NT; ++u) acc[t][u] = (floatx4){0.f, 0.f, 0.f, 0.f};

            const bf16* h1r = (e & 1) ? h1b1 : h1b0;
            if (layer == 0) {
                const bf16* xt = xb + (size_t)e * B_ * KX_;
                seg(xt, KX_, IC<5>{}, 0);
                seg(h1r, H_, IC<32>{}, 5);
            } else {
                const bf16* h2r = (e & 1) ? h2b0 : h2b1;
                seg(h1r, H_, IC<32>{}, 0);
                seg(h2r, H_, IC<32>{}, 32);
            }
            bf16* hw = (layer == 0) ? ((e & 1) ? h1b0 : h1b1)
                                    : ((e & 1) ? h2b1 : h2b0);

            const int base = lane & 48;
#pragma unroll
            for (int t = 0; t < 2; ++t) {
#pragma unroll
                for (int r = 0; r < 4; ++r) {
                    float vi = __shfl(acc[t][0][r], base + jj, 64);
                    float vf = __shfl(acc[t][0][r], base + 8 + jj, 64);
                    float vg = __shfl(acc[t][1][r], base + jj, 64);
                    float vo = __shfl(acc[t][1][r], base + 8 + jj, 64);
                    bool cond = (((lane >> 3) & 1) == (r & 1));
                    int slot = t * 2 + (r >> 1);
                    if (cond) {
                        float cv = creg[slot];
                        float cn = sigmoidf_(vf + bias.y) * cv
                                 + sigmoidf_(vi + bias.x) * tanhf(vg + bias.z);
                        creg[slot] = cn;
                        float hn = sigmoidf_(vo + bias.w) * tanhf(cn);
                        hst[wv][t * 16 + quad * 4 + r][jj] = (bf16)hn;
                    }
                }
            }
            __syncthreads();
            if (lane < 64) {
                int row_l = lane >> 1, cg = lane & 1;
                ull v = *(const ull*)&hst[wv][row_l][cg * 4];
                __hip_atomic_store((ull*)(hw + (size_t)(wv * 32 + row_l) * H_ + n0h + cg * 4),
                                   v, __ATOMIC_RELAXED, __HIP_MEMORY_SCOPE_AGENT);
            }
        }

        asm volatile("s_waitcnt vmcnt(0)" ::: "memory");
        __syncthreads();
        const unsigned etag = (unsigned)(e + 1);
        if (bid == 0) {
            if (tid == 0)
                __hip_atomic_fetch_add(cnt, 1u, __ATOMIC_RELAXED, __HIP_MEMORY_SCOPE_AGENT);
            if (tid < 8) {
                const unsigned tgt = etag * (unsigned)arr_per_line;
                const unsigned* cp = cnt + tid * CSTRIDE;
                while (__hip_atomic_load(cp, __ATOMIC_RELAXED, __HIP_MEMORY_SCOPE_AGENT) < tgt)
                    __builtin_amdgcn_s_sleep(1);
            }
            if (tid == 0)
                __hip_atomic_store(cnt + 8 * CSTRIDE, etag,
                                   __ATOMIC_RELAXED, __HIP_MEMORY_SCOPE_AGENT);
        } else {
            if (tid == 0) {
                __hip_atomic_fetch_add(cnt + (bid & 7) * CSTRIDE, 1u,
                                       __ATOMIC_RELAXED, __HIP_MEMORY_SCOPE_AGENT);
                const unsigned* fp = cnt + 8 * CSTRIDE;
                while (__hip_atomic_load(fp, __ATOMIC_RELAXED, __HIP_MEMORY_SCOPE_AGENT) < etag)
                    __builtin_amdgcn_s_sleep(1);
            }
        }
        __syncthreads();
        if (tid < 64)
            __builtin_amdgcn_fence(__ATOMIC_ACQUIRE, "agent");
        __syncthreads();
    }

    if (bid < B_) {
        const bf16* h2f = h2b0;
        for (int c = wv; c < C_; c += 4) {
            float a = 0.f;
            for (int k = lane; k < H_; k += 64)
                a += (float)h2f[(size_t)bid * H_ + k] * Wfc[(size_t)c * H_ + k];
#pragma unroll
            for (int off = 32; off; off >>= 1) a += __shfl_down(a, off, 64);
            if (lane == 0) out[bid * C_ + c] = a + bfc[c];
        }
    }
}

extern "C" void kernel_launch(void* const* d_in, const int* in_sizes, int n_in,
                              void* d_out, int out_size, void* d_ws, size_t ws_size,
                              hipStream_t stream)
{
    const float* x    = (const float*)d_in[0];
    const float* h1in = (const float*)d_in[1];
    const float* c1in = (const float*)d_in[2];
    const float* h2in = (const float*)d_in[3];
    const float* c2in = (const float*)d_in[4];
    const float* Wih1 = (const float*)d_in[5];
    const float* Whh1 = (const float*)d_in[6];
    const float* bih1 = (const float*)d_in[7];
    const float* bhh1 = (const float*)d_in[8];
    const float* Wih2 = (const float*)d_in[9];
    const float* Whh2 = (const float*)d_in[10];
    const float* bih2 = (const float*)d_in[11];
    const float* bhh2 = (const float*)d_in[12];
    const float* Wfc  = (const float*)d_in[13];
    const float* bfc  = (const float*)d_in[14];
    float* out = (float*)d_out;

    // ws carve (~11.5 MB)
    char* p = (char*)d_ws;
    bf16* xb = (bf16*)p;    p += (size_t)T_ * B_ * KX_ * 2;
    bf16* h1b0 = (bf16*)p;  p += (size_t)B_ * H_ * 2;
    bf16* h1b1 = (bf16*)p;  p += (size_t)B_ * H_ * 2;
    bf16* h2b0 = (bf16*)p;  p += (size_t)B_ * H_ * 2;
    bf16* h2b1 = (bf16*)p;  p += (size_t)B_ * H_ * 2;
    unsigned* cnt = (unsigned*)p;       // 16 lines x 256B

    const size_t citems = (size_t)T_ * B_ * KX_ + 2 * (size_t)B_ * H_ + NLINES * CSTRIDE;
    convert_all<<<(int)((citems + 255) / 256), 256, 0, stream>>>(
        x, h1in, h2in, xb, h1b0, h2b0, cnt);

    int nblk = 256;
    void* args[] = { &xb, &h1b0, &h1b1, &h2b0, &h2b1, (void*)&c1in, (void*)&c2in,
                     (void*)&Wih1, (void*)&Whh1, (void*)&bih1, (void*)&bhh1,
                     (void*)&Wih2, (void*)&Whh2, (void*)&bih2, (void*)&bhh2,
                     (void*)&Wfc, (void*)&bfc, &out, &cnt, &nblk };

    (void)hipFuncSetAttribute((const void*)rnn_persistent8,
                              hipFuncAttributeMaxDynamicSharedMemorySize, 131072);
    hipError_t err = hipLaunchCooperativeKernel((const void*)rnn_persistent8,
                                                dim3(256), dim3(512), args,
                                                131072u, stream);
    if (err != hipSuccess) {
        (void)hipGetLastError();
        (void)hipFuncSetAttribute((const void*)rnn_persistent4,
                                  hipFuncAttributeMaxDynamicSharedMemorySize, 131072);
        (void)hipLaunchCooperativeKernel((const void*)rnn_persistent4,
                                         dim3(256), dim3(256), args,
                                         131072u, stream);
    }
}

// Round 6
// 3582.369 us; speedup vs baseline: 1.7169x; 1.4348x over previous
//
#include <hip/hip_runtime.h>
#include <math.h>

// stacked_rnn R12: R11 (layer rebalance via partial-sum donation), hardened.
// R11's bench died at container level; prime suspect = workspace overflow
// (R11 needed ~15.7MB vs ~11.5MB historical usage, ws_size never checked).
// R12: (1) ws_size guard — p-buffers only used if workspace fits;
// (2) fallback is the PROVEN R10 8-wave kernel (5140us) for both the
// ws-too-small and LDS-launch-fail paths; (3) single shared signature.
// Rebalance theory unchanged: GEMM phase = max(L0,L1); L1 streams 512KB/blk
// (h1+h2) vs L0 296KB (x+h1). L0 donates p(e)=Wih2·h1(e) as a second MFMA
// per h1 chunk (zero extra stream, Wih2 slice LDS-resident, L0 LDS=144KB),
// publishing p (f32 16KB/slice) via the proven store/fence protocol. L1 then
// streams only h2 + reads its p slice (272KB), skewed one epoch (258 epochs).

typedef __bf16 bf16;
typedef __bf16 bf16x8 __attribute__((ext_vector_type(8)));
typedef float floatx4 __attribute__((ext_vector_type(4)));
typedef unsigned long long ull;

#define B_   128
#define T_   256
#define H_   1024
#define I_   150
#define KX_  160
#define C_   60
#define K1LDS 1280   // L0 W1 LDS row width in elems (x 160 + h1 1024 + pad)
#define KP    1024   // Wih2 / Whh2 LDS row width
#define K2LDS 2048   // fallback kernel layer-2 row width
#define NLINES 16    // counter lines
#define CSTRIDE 64   // uints between lines (256B)
#define NCOLS 32     // gate-cols per block tile
#define NHC  8       // h-cols per block (NCOLS/4)
#define NT   2       // N-tiles of 16

template<int N> struct IC { static constexpr int value = N; };

__device__ __forceinline__ float sigmoidf_(float x) { return 1.f / (1.f + expf(-x)); }

// ---------------- conversion / init kernel ----------------
__global__ __launch_bounds__(256)
void convert_all(const float* __restrict__ x,
                 const float* __restrict__ h1in, const float* __restrict__ h2in,
                 bf16* __restrict__ xb, bf16* __restrict__ h1b0, bf16* __restrict__ h2b0,
                 unsigned* __restrict__ cnt)
{
    const size_t nXB = (size_t)T_ * B_ * KX_;   // 5242880
    const size_t nHC = (size_t)B_ * H_;         // 131072
    size_t idx = (size_t)blockIdx.x * 256 + threadIdx.x;

    if (idx < nXB) {                            // x [B][T][150] -> xb [T][B][160]
        size_t t = idx / (B_ * KX_);
        size_t r = idx - t * (B_ * KX_);
        size_t b = r / KX_, k = r - b * KX_;
        xb[idx] = (k < I_) ? (bf16)x[(b * T_ + t) * I_ + k] : (bf16)0.f;
        return;
    }
    idx -= nXB;
    if (idx < nHC) { h1b0[idx] = (bf16)h1in[idx]; return; }
    idx -= nHC;
    if (idx < nHC) { h2b0[idx] = (bf16)h2in[idx]; return; }
    idx -= nHC;
    if (idx < NLINES * CSTRIDE) cnt[idx] = 0u;
}

// ================= R12 primary: 8-wave rebalanced persistent kernel =========
// 256 blocks = 2 layers x 128 slices. layer=(bid>>3)&1, slice=(bid&7)|((bid>>4)<<3).
// L0 block s: LDS = W1 (32 x 1280) + Wih2 slice (32 x 1024) = 144KB.
//   epoch e in [0,T_]: stream x(e) [e<T_] + h1(e); compute h1(e+1) slice AND
//   p(e) = Wih2_s·h1(e) (f32); publish both.
// L1 block s: LDS = Whh2 slice (32 x 1024) = 64KB.
//   epoch e in [2,T_+1]: stream h2(e-2); acc += p(e-1) slice; compute h2(e-1).
__global__ __launch_bounds__(512, 2)
void rnn_rebal8(const bf16* __restrict__ xb,
                bf16* __restrict__ h1b0, bf16* __restrict__ h1b1,
                bf16* __restrict__ h2b0, bf16* __restrict__ h2b1,
                float* __restrict__ p0, float* __restrict__ p1,
                const float* __restrict__ c1in, const float* __restrict__ c2in,
                const float* __restrict__ Wih1, const float* __restrict__ Whh1,
                const float* __restrict__ bih1, const float* __restrict__ bhh1,
                const float* __restrict__ Wih2, const float* __restrict__ Whh2,
                const float* __restrict__ bih2, const float* __restrict__ bhh2,
                const float* __restrict__ Wfc, const float* __restrict__ bfc,
                float* __restrict__ out, unsigned* __restrict__ cnt, int nblk)
{
    extern __shared__ bf16 lds[];
    __shared__ __align__(16) bf16 hst[8][16][NHC];   // epilogue staging

    const int tid   = threadIdx.x;
    const int bid   = blockIdx.x;
    const int layer = (bid >> 3) & 1;
    const int slice = (bid & 7) | ((bid >> 4) << 3);
    const int n0h   = slice * NHC;
    const int arr_per_line = nblk >> 3;
    bf16* ldsP = lds + 32 * K1LDS;      // L0's Wih2 region

    // ---- stage weights fp32->bf16 into swizzled LDS (once) ----
    if (layer == 0) {
        {   // W1 region: 32 rows x K1LDS (x [0,160), h1 [160,1184), pad)
            const int cpr = K1LDS >> 3;           // 160
            const int total = NCOLS * cpr;
            for (int ci = tid; ci < total; ci += 512) {
                int r = ci / cpr, c = ci - r * cpr;
                int g = r / NHC, j = r - g * NHC;
                int grow = (g << 10) + n0h + j;
                int k0 = c << 3;
                float v[8];
#pragma unroll
                for (int u = 0; u < 8; ++u) {
                    int k = k0 + u;
                    v[u] = (k < I_) ? Wih1[(size_t)grow * I_ + k]
                         : (k < KX_) ? 0.f
                         : (k < KX_ + H_) ? Whh1[(size_t)grow * H_ + (k - KX_)] : 0.f;
                }
                int cs = (c & ~15) | ((c ^ r) & 15);
                bf16* dst = lds + (size_t)r * K1LDS + (cs << 3);
#pragma unroll
                for (int u = 0; u < 8; ++u) dst[u] = (bf16)v[u];
            }
        }
        {   // Wih2 region: 32 rows x KP
            const int cpr = KP >> 3;              // 128
            const int total = NCOLS * cpr;
            for (int ci = tid; ci < total; ci += 512) {
                int r = ci / cpr, c = ci - r * cpr;
                int g = r / NHC, j = r - g * NHC;
                int grow = (g << 10) + n0h + j;
                int k0 = c << 3;
                float v[8];
#pragma unroll
                for (int u = 0; u < 8; ++u) v[u] = Wih2[(size_t)grow * H_ + k0 + u];
                int cs = (c & ~15) | ((c ^ r) & 15);
                bf16* dst = ldsP + (size_t)r * KP + (cs << 3);
#pragma unroll
                for (int u = 0; u < 8; ++u) dst[u] = (bf16)v[u];
            }
        }
    } else {
        // Whh2 region: 32 rows x KP
        const int cpr = KP >> 3;
        const int total = NCOLS * cpr;
        for (int ci = tid; ci < total; ci += 512) {
            int r = ci / cpr, c = ci - r * cpr;
            int g = r / NHC, j = r - g * NHC;
            int grow = (g << 10) + n0h + j;
            int k0 = c << 3;
            float v[8];
#pragma unroll
            for (int u = 0; u < 8; ++u) v[u] = Whh2[(size_t)grow * H_ + k0 + u];
            int cs = (c & ~15) | ((c ^ r) & 15);
            bf16* dst = lds + (size_t)r * KP + (cs << 3);
#pragma unroll
            for (int u = 0; u < 8; ++u) dst[u] = (bf16)v[u];
        }
    }
    __syncthreads();

    const int lane = tid & 63;
    const int wv   = tid >> 6;          // 0..7
    const int jj   = lane & (NHC - 1);
    const int quad = lane >> 4;

    float4 bias;
    {
        const float* bi = layer ? bih2 : bih1;
        const float* bh = layer ? bhh2 : bhh1;
        int col = n0h + jj;
        bias.x = bi[col] + bh[col];
        bias.y = bi[col + H_] + bh[col + H_];
        bias.z = bi[col + 2 * H_] + bh[col + 2 * H_];
        bias.w = bi[col + 3 * H_] + bh[col + 3 * H_];
    }

    float creg[2];
    {
        const float* cin = layer ? c2in : c1in;
        int dup = (lane >> 3) & 1;
#pragma unroll
        for (int rp = 0; rp < 2; ++rp) {
            int row = wv * 16 + quad * 4 + rp * 2 + dup;
            creg[rp] = cin[(size_t)row * H_ + n0h + jj];
        }
    }

    floatx4 acc[NT];
    floatx4 pacc[NT];

    // generic single-target K-segment (R10 structure, sched_barrier pin)
    auto seg1 = [&](const bf16* A, int ldA, const bf16* Bb, int ldB,
                    auto nksC, int ksBase) {
        constexpr int NKS = decltype(nksC)::value;
        constexpr int CH  = NKS < 16 ? NKS : 16;
        const int arow = wv * 16 + (lane & 15);
        const bf16* a0 = A + (size_t)arow * ldA + quad * 8;
        for (int blk = 0; blk < NKS; blk += CH) {
            bf16x8 a0r[CH];
#pragma unroll
            for (int i = 0; i < CH; ++i)
                a0r[i] = *(const bf16x8*)(a0 + (blk + i) * 32);
            __builtin_amdgcn_sched_barrier(0);
#pragma unroll
            for (int i = 0; i < CH; ++i) {
                int c = (ksBase + blk + i) * 4 + quad;
#pragma unroll
                for (int t = 0; t < NT; ++t) {
                    int r = t * 16 + (lane & 15);
                    int cs = (c & ~15) | ((c ^ r) & 15);
                    bf16x8 bfr = *(const bf16x8*)(Bb + (size_t)r * ldB + (cs << 3));
                    acc[t] = __builtin_amdgcn_mfma_f32_16x16x32_bf16(a0r[i], bfr, acc[t], 0, 0, 0);
                }
            }
        }
    };

    // dual-target h1-segment (L0): gates1 into acc (W1, ksBase 5) AND
    // p into pacc (Wih2, ksBase 0) from the SAME A stream.
    auto segDual = [&](const bf16* A) {
        const int arow = wv * 16 + (lane & 15);
        const bf16* a0 = A + (size_t)arow * H_ + quad * 8;
        for (int blk = 0; blk < 32; blk += 16) {
            bf16x8 a0r[16];
#pragma unroll
            for (int i = 0; i < 16; ++i)
                a0r[i] = *(const bf16x8*)(a0 + (blk + i) * 32);
            __builtin_amdgcn_sched_barrier(0);
#pragma unroll
            for (int i = 0; i < 16; ++i) {
                int ig = blk + i;
                int c1 = (5 + ig) * 4 + quad;
                int cp = ig * 4 + quad;
#pragma unroll
                for (int t = 0; t < NT; ++t) {
                    int r = t * 16 + (lane & 15);
                    int cs1 = (c1 & ~15) | ((c1 ^ r) & 15);
                    bf16x8 b1 = *(const bf16x8*)(lds + (size_t)r * K1LDS + (cs1 << 3));
                    acc[t] = __builtin_amdgcn_mfma_f32_16x16x32_bf16(a0r[i], b1, acc[t], 0, 0, 0);
                    int csp = (cp & ~15) | ((cp ^ r) & 15);
                    bf16x8 bp = *(const bf16x8*)(ldsP + (size_t)r * KP + (csp << 3));
                    pacc[t] = __builtin_amdgcn_mfma_f32_16x16x32_bf16(a0r[i], bp, pacc[t], 0, 0, 0);
                }
            }
        }
    };

    // epilogue: shfl-gather gates, update creg, stage h to LDS, store h
    auto epilogue = [&](bf16* hw) {
        const int base = lane & 48;
#pragma unroll
        for (int r = 0; r < 4; ++r) {
            float vi = __shfl(acc[0][r], base + jj, 64);
            float vf = __shfl(acc[0][r], base + 8 + jj, 64);
            float vg = __shfl(acc[1][r], base + jj, 64);
            float vo = __shfl(acc[1][r], base + 8 + jj, 64);
            bool cond = (((lane >> 3) & 1) == (r & 1));
            int slot = r >> 1;
            if (cond) {
                float cv = creg[slot];
                float cn = sigmoidf_(vf + bias.y) * cv
                         + sigmoidf_(vi + bias.x) * tanhf(vg + bias.z);
                creg[slot] = cn;
                float hn = sigmoidf_(vo + bias.w) * tanhf(cn);
                hst[wv][quad * 4 + r][jj] = (bf16)hn;
            }
        }
        __syncthreads();
        if (lane < 32) {
            int row_l = lane >> 1, cg = lane & 1;
            ull v = *(const ull*)&hst[wv][row_l][cg * 4];
            __hip_atomic_store((ull*)(hw + (size_t)(wv * 16 + row_l) * H_ + n0h + cg * 4),
                               v, __ATOMIC_RELAXED, __HIP_MEMORY_SCOPE_AGENT);
        }
    };

    for (int e = 0; e <= T_ + 1; ++e) {
        if (layer == 0 && e <= T_) {
#pragma unroll
            for (int t = 0; t < NT; ++t) {
                acc[t]  = (floatx4){0.f, 0.f, 0.f, 0.f};
                pacc[t] = (floatx4){0.f, 0.f, 0.f, 0.f};
            }
            const bf16* h1r = (e & 1) ? h1b1 : h1b0;          // h1^(e)
            if (e < T_) {
                const bf16* xt = xb + (size_t)e * B_ * KX_;
                seg1(xt, KX_, lds, K1LDS, IC<5>{}, 0);
            }
            segDual(h1r);                                      // gates1 + p(e)

            // publish p(e) slice (f32, relaxed-agent write-through)
            float* pw = ((e & 1) ? p1 : p0) + (size_t)slice * B_ * NCOLS;
#pragma unroll
            for (int t = 0; t < NT; ++t)
#pragma unroll
                for (int r = 0; r < 4; ++r) {
                    int row = wv * 16 + quad * 4 + r;
                    __hip_atomic_store(pw + (size_t)row * NCOLS + t * 16 + (lane & 15),
                                       pacc[t][r], __ATOMIC_RELAXED, __HIP_MEMORY_SCOPE_AGENT);
                }

            if (e < T_) {
                bf16* hw = (e & 1) ? h1b0 : h1b1;              // h1^(e+1)
                epilogue(hw);
            }
        } else if (layer == 1 && e >= 2) {
#pragma unroll
            for (int t = 0; t < NT; ++t) acc[t] = (floatx4){0.f, 0.f, 0.f, 0.f};
            const bf16* h2r = (e & 1) ? h2b1 : h2b0;           // h2^(e-2)
            seg1(h2r, H_, lds, KP, IC<32>{}, 0);

            // add p(e-1) slice (plain loads; coherent after barrier+fence)
            const float* pr = ((e & 1) ? p0 : p1) + (size_t)slice * B_ * NCOLS;
#pragma unroll
            for (int t = 0; t < NT; ++t)
#pragma unroll
                for (int r = 0; r < 4; ++r) {
                    int row = wv * 16 + quad * 4 + r;
                    acc[t][r] += pr[(size_t)row * NCOLS + t * 16 + (lane & 15)];
                }

            bf16* hw = (e & 1) ? h2b0 : h2b1;                  // h2^(e-1)
            epilogue(hw);
        }

        // ---- two-level barrier: RMW lines (0..7) + broadcast flag line (8) ----
        asm volatile("s_waitcnt vmcnt(0)" ::: "memory");
        __syncthreads();
        const unsigned etag = (unsigned)(e + 1);
        if (bid == 0) {
            if (tid == 0)
                __hip_atomic_fetch_add(cnt, 1u, __ATOMIC_RELAXED, __HIP_MEMORY_SCOPE_AGENT);
            if (tid < 8) {
                const unsigned tgt = etag * (unsigned)arr_per_line;
                const unsigned* cp = cnt + tid * CSTRIDE;
                while (__hip_atomic_load(cp, __ATOMIC_RELAXED, __HIP_MEMORY_SCOPE_AGENT) < tgt)
                    __builtin_amdgcn_s_sleep(1);
            }
            if (tid == 0)
                __hip_atomic_store(cnt + 8 * CSTRIDE, etag,
                                   __ATOMIC_RELAXED, __HIP_MEMORY_SCOPE_AGENT);
        } else {
            if (tid == 0) {
                __hip_atomic_fetch_add(cnt + (bid & 7) * CSTRIDE, 1u,
                                       __ATOMIC_RELAXED, __HIP_MEMORY_SCOPE_AGENT);
                const unsigned* fp = cnt + 8 * CSTRIDE;
                while (__hip_atomic_load(fp, __ATOMIC_RELAXED, __HIP_MEMORY_SCOPE_AGENT) < etag)
                    __builtin_amdgcn_s_sleep(1);
            }
        }
        __syncthreads();
        // acquire (cache inv) by wave 0 only: invalidates this CU's L1 + XCD L2
        if (tid < 64)
            __builtin_amdgcn_fence(__ATOMIC_ACQUIRE, "agent");
        __syncthreads();
    }

    // ---- fused FC: out = h2^(256) @ Wfc^T + bfc ; h2^(256) is in h2b0 ----
    if (bid < B_) {
        const bf16* h2f = h2b0;
        for (int c = wv; c < C_; c += 8) {
            float a = 0.f;
            for (int k = lane; k < H_; k += 64)
                a += (float)h2f[(size_t)bid * H_ + k] * Wfc[(size_t)c * H_ + k];
#pragma unroll
            for (int off = 32; off; off >>= 1) a += __shfl_down(a, off, 64);
            if (lane == 0) out[bid * C_ + c] = a + bfc[c];
        }
    }
}

// ============ fallback: PROVEN R10 8-wave kernel (5140us, passed) ===========
// Same signature as primary; p0/p1 unused. Original R6 dataflow.
__global__ __launch_bounds__(512, 2)
void rnn_fallback8(const bf16* __restrict__ xb,
                   bf16* __restrict__ h1b0, bf16* __restrict__ h1b1,
                   bf16* __restrict__ h2b0, bf16* __restrict__ h2b1,
                   float* __restrict__ p0, float* __restrict__ p1,
                   const float* __restrict__ c1in, const float* __restrict__ c2in,
                   const float* __restrict__ Wih1, const float* __restrict__ Whh1,
                   const float* __restrict__ bih1, const float* __restrict__ bhh1,
                   const float* __restrict__ Wih2, const float* __restrict__ Whh2,
                   const float* __restrict__ bih2, const float* __restrict__ bhh2,
                   const float* __restrict__ Wfc, const float* __restrict__ bfc,
                   float* __restrict__ out, unsigned* __restrict__ cnt, int nblk)
{
    extern __shared__ bf16 lds[];
    __shared__ __align__(16) bf16 hst[8][16][NHC];

    const int tid   = threadIdx.x;
    const int bid   = blockIdx.x;
    const int layer = (bid >> 3) & 1;
    const int slice = (bid & 7) | ((bid >> 4) << 3);
    const int n0h   = slice * NHC;
    const int KLDS  = layer ? K2LDS : K1LDS;
    const int arr_per_line = nblk >> 3;

    {   // stage weights (R6 combined map)
        const int cpr = KLDS >> 3;
        const int total = NCOLS * cpr;
        for (int ci = tid; ci < total; ci += 512) {
            int r = ci / cpr, c = ci - r * cpr;
            int g = r / NHC, j = r - g * NHC;
            int grow = (g << 10) + n0h + j;
            int k0 = c << 3;
            float v[8];
#pragma unroll
            for (int u = 0; u < 8; ++u) {
                int k = k0 + u;
                if (layer == 0)
                    v[u] = (k < I_) ? Wih1[(size_t)grow * I_ + k]
                         : (k < KX_) ? 0.f
                         : (k < KX_ + H_) ? Whh1[(size_t)grow * H_ + (k - KX_)] : 0.f;
                else
                    v[u] = (k < H_) ? Wih2[(size_t)grow * H_ + k]
                                    : Whh2[(size_t)grow * H_ + (k - H_)];
            }
            int cs = (c & ~15) | ((c ^ r) & 15);
            bf16* dst = lds + (size_t)r * KLDS + (cs << 3);
#pragma unroll
            for (int u = 0; u < 8; ++u) dst[u] = (bf16)v[u];
        }
    }
    __syncthreads();

    const int lane = tid & 63;
    const int wv   = tid >> 6;
    const int jj   = lane & (NHC - 1);
    const int quad = lane >> 4;

    float4 bias;
    {
        const float* bi = layer ? bih2 : bih1;
        const float* bh = layer ? bhh2 : bhh1;
        int col = n0h + jj;
        bias.x = bi[col] + bh[col];
        bias.y = bi[col + H_] + bh[col + H_];
        bias.z = bi[col + 2 * H_] + bh[col + 2 * H_];
        bias.w = bi[col + 3 * H_] + bh[col + 3 * H_];
    }

    float creg[2];
    {
        const float* cin = layer ? c2in : c1in;
        int dup = (lane >> 3) & 1;
#pragma unroll
        for (int rp = 0; rp < 2; ++rp) {
            int row = wv * 16 + quad * 4 + rp * 2 + dup;
            creg[rp] = cin[(size_t)row * H_ + n0h + jj];
        }
    }

    floatx4 acc[NT];

    auto seg = [&](const bf16* A, int ldA, auto nksC, int ksBase) {
        constexpr int NKS = decltype(nksC)::value;
        constexpr int CH  = NKS < 16 ? NKS : 16;
        const int arow = wv * 16 + (lane & 15);
        const bf16* a0 = A + (size_t)arow * ldA + quad * 8;
        for (int blk = 0; blk < NKS; blk += CH) {
            bf16x8 a0r[CH];
#pragma unroll
            for (int i = 0; i < CH; ++i)
                a0r[i] = *(const bf16x8*)(a0 + (blk + i) * 32);
            __builtin_amdgcn_sched_barrier(0);
#pragma unroll
            for (int i = 0; i < CH; ++i) {
                int c = (ksBase + blk + i) * 4 + quad;
#pragma unroll
                for (int t = 0; t < NT; ++t) {
                    int r = t * 16 + (lane & 15);
                    int cs = (c & ~15) | ((c ^ r) & 15);
                    bf16x8 bfr = *(const bf16x8*)(lds + (size_t)r * KLDS + (cs << 3));
                    acc[t] = __builtin_amdgcn_mfma_f32_16x16x32_bf16(a0r[i], bfr, acc[t], 0, 0, 0);
                }
            }
        }
    };

    for (int e = 0; e <= T_; ++e) {
        const bool active = layer == 0 ? (e < T_) : (e >= 1);
        if (active) {
#pragma unroll
            for (int t = 0; t < NT; ++t) acc[t] = (floatx4){0.f, 0.f, 0.f, 0.f};

            const bf16* h1r = (e & 1) ? h1b1 : h1b0;
            if (layer == 0) {
                const bf16* xt = xb + (size_t)e * B_ * KX_;
                seg(xt, KX_, IC<5>{}, 0);
                seg(h1r, H_, IC<32>{}, 5);
            } else {
                const bf16* h2r = (e & 1) ? h2b0 : h2b1;
                seg(h1r, H_, IC<32>{}, 0);
                seg(h2r, H_, IC<32>{}, 32);
            }
            bf16* hw = (layer == 0) ? ((e & 1) ? h1b0 : h1b1)
                                    : ((e & 1) ? h2b1 : h2b0);

            const int base = lane & 48;
#pragma unroll
            for (int r = 0; r < 4; ++r) {
                float vi = __shfl(acc[0][r], base + jj, 64);
                float vf = __shfl(acc[0][r], base + 8 + jj, 64);
                float vg = __shfl(acc[1][r], base + jj, 64);
                float vo = __shfl(acc[1][r], base + 8 + jj, 64);
                bool cond = (((lane >> 3) & 1) == (r & 1));
                int slot = r >> 1;
                if (cond) {
                    float cv = creg[slot];
                    float cn = sigmoidf_(vf + bias.y) * cv
                             + sigmoidf_(vi + bias.x) * tanhf(vg + bias.z);
                    creg[slot] = cn;
                    float hn = sigmoidf_(vo + bias.w) * tanhf(cn);
                    hst[wv][quad * 4 + r][jj] = (bf16)hn;
                }
            }
            __syncthreads();
            if (lane < 32) {
                int row_l = lane >> 1, cg = lane & 1;
                ull v = *(const ull*)&hst[wv][row_l][cg * 4];
                __hip_atomic_store((ull*)(hw + (size_t)(wv * 16 + row_l) * H_ + n0h + cg * 4),
                                   v, __ATOMIC_RELAXED, __HIP_MEMORY_SCOPE_AGENT);
            }
        }

        asm volatile("s_waitcnt vmcnt(0)" ::: "memory");
        __syncthreads();
        const unsigned etag = (unsigned)(e + 1);
        if (bid == 0) {
            if (tid == 0)
                __hip_atomic_fetch_add(cnt, 1u, __ATOMIC_RELAXED, __HIP_MEMORY_SCOPE_AGENT);
            if (tid < 8) {
                const unsigned tgt = etag * (unsigned)arr_per_line;
                const unsigned* cp = cnt + tid * CSTRIDE;
                while (__hip_atomic_load(cp, __ATOMIC_RELAXED, __HIP_MEMORY_SCOPE_AGENT) < tgt)
                    __builtin_amdgcn_s_sleep(1);
            }
            if (tid == 0)
                __hip_atomic_store(cnt + 8 * CSTRIDE, etag,
                                   __ATOMIC_RELAXED, __HIP_MEMORY_SCOPE_AGENT);
        } else {
            if (tid == 0) {
                __hip_atomic_fetch_add(cnt + (bid & 7) * CSTRIDE, 1u,
                                       __ATOMIC_RELAXED, __HIP_MEMORY_SCOPE_AGENT);
                const unsigned* fp = cnt + 8 * CSTRIDE;
                while (__hip_atomic_load(fp, __ATOMIC_RELAXED, __HIP_MEMORY_SCOPE_AGENT) < etag)
                    __builtin_amdgcn_s_sleep(1);
            }
        }
        __syncthreads();
        if (tid < 64)
            __builtin_amdgcn_fence(__ATOMIC_ACQUIRE, "agent");
        __syncthreads();
    }

    if (bid < B_) {
        const bf16* h2f = h2b0;
        for (int c = wv; c < C_; c += 8) {
            float a = 0.f;
            for (int k = lane; k < H_; k += 64)
                a += (float)h2f[(size_t)bid * H_ + k] * Wfc[(size_t)c * H_ + k];
#pragma unroll
            for (int off = 32; off; off >>= 1) a += __shfl_down(a, off, 64);
            if (lane == 0) out[bid * C_ + c] = a + bfc[c];
        }
    }
}

extern "C" void kernel_launch(void* const* d_in, const int* in_sizes, int n_in,
                              void* d_out, int out_size, void* d_ws, size_t ws_size,
                              hipStream_t stream)
{
    const float* x    = (const float*)d_in[0];
    const float* h1in = (const float*)d_in[1];
    const float* c1in = (const float*)d_in[2];
    const float* h2in = (const float*)d_in[3];
    const float* c2in = (const float*)d_in[4];
    const float* Wih1 = (const float*)d_in[5];
    const float* Whh1 = (const float*)d_in[6];
    const float* bih1 = (const float*)d_in[7];
    const float* bhh1 = (const float*)d_in[8];
    const float* Wih2 = (const float*)d_in[9];
    const float* Whh2 = (const float*)d_in[10];
    const float* bih2 = (const float*)d_in[11];
    const float* bhh2 = (const float*)d_in[12];
    const float* Wfc  = (const float*)d_in[13];
    const float* bfc  = (const float*)d_in[14];
    float* out = (float*)d_out;

    // ws carve: base ~11.5MB always; p buffers (+4MB) only if ws fits
    const size_t szXB  = (size_t)T_ * B_ * KX_ * 2;        // 10485760
    const size_t szH   = (size_t)B_ * H_ * 2;              // 262144
    const size_t szCnt = (size_t)NLINES * CSTRIDE * 4;     // 4096
    const size_t szP   = (size_t)128 * B_ * NCOLS * 4;     // 2097152
    const size_t needBase  = szXB + 4 * szH + szCnt;
    const size_t needRebal = needBase + 2 * szP;

    char* p = (char*)d_ws;
    bf16* xb = (bf16*)p;    p += szXB;
    bf16* h1b0 = (bf16*)p;  p += szH;
    bf16* h1b1 = (bf16*)p;  p += szH;
    bf16* h2b0 = (bf16*)p;  p += szH;
    bf16* h2b1 = (bf16*)p;  p += szH;
    unsigned* cnt = (unsigned*)p;  p += szCnt;
    float* p0 = (float*)p;  p += szP;
    float* p1 = (float*)p;

    const size_t citems = (size_t)T_ * B_ * KX_ + 2 * (size_t)B_ * H_ + NLINES * CSTRIDE;
    convert_all<<<(int)((citems + 255) / 256), 256, 0, stream>>>(
        x, h1in, h2in, xb, h1b0, h2b0, cnt);

    int nblk = 256;
    void* args[] = { &xb, &h1b0, &h1b1, &h2b0, &h2b1, &p0, &p1,
                     (void*)&c1in, (void*)&c2in,
                     (void*)&Wih1, (void*)&Whh1, (void*)&bih1, (void*)&bhh1,
                     (void*)&Wih2, (void*)&Whh2, (void*)&bih2, (void*)&bhh2,
                     (void*)&Wfc, (void*)&bfc, &out, &cnt, &nblk };

    hipError_t err = hipErrorOutOfMemory;
    if (ws_size >= needRebal) {
        const unsigned ldsRebal = (unsigned)(32 * K1LDS + 32 * KP) * 2u;  // 147456
        if (hipFuncSetAttribute((const void*)rnn_rebal8,
                                hipFuncAttributeMaxDynamicSharedMemorySize,
                                (int)ldsRebal) == hipSuccess) {
            err = hipLaunchCooperativeKernel((const void*)rnn_rebal8,
                                             dim3(256), dim3(512), args,
                                             ldsRebal, stream);
        }
    }
    if (err != hipSuccess) {
        (void)hipGetLastError();
        (void)hipFuncSetAttribute((const void*)rnn_fallback8,
                                  hipFuncAttributeMaxDynamicSharedMemorySize, 131072);
        (void)hipLaunchCooperativeKernel((const void*)rnn_fallback8,
                                         dim3(256), dim3(512), args,
                                         131072u, stream);
    }
}

// Round 7
// 3548.395 us; speedup vs baseline: 1.7333x; 1.0096x over previous
//
#include <hip/hip_runtime.h>
#include <math.h>

// stacked_rnn R13: R12 (rebalanced, 3582us proven) + barrier-dead-time fill.
// Changes vs R12 (protocol semantics unchanged):
//  (1) L0 overlaps next-epoch x-seg (immutable input: 5 chunks + 10 MFMAs)
//      into the barrier window between its arrive-RMW and the flag poll —
//      work that previously sat on the post-fence critical path.
//  (2) 16 arrive lines (was 8): halves same-line RMW serialization.
//  (3) L1 prefetches its 8 p-scalars into registers before the h2-seg so
//      their LLC latency hides under the seg.
// Fallback chain unchanged: ws-size guard + proven R10 8-wave kernel.

typedef __bf16 bf16;
typedef __bf16 bf16x8 __attribute__((ext_vector_type(8)));
typedef float floatx4 __attribute__((ext_vector_type(4)));
typedef unsigned long long ull;

#define B_   128
#define T_   256
#define H_   1024
#define I_   150
#define KX_  160
#define C_   60
#define K1LDS 1280   // L0 W1 LDS row width in elems (x 160 + h1 1024 + pad)
#define KP    1024   // Wih2 / Whh2 LDS row width
#define K2LDS 2048   // fallback kernel layer-2 row width
#define NLINES 32    // zeroed counter lines (primary uses 0..15 + flag @16;
                     // fallback uses 0..7 + flag @8)
#define CSTRIDE 64   // uints between lines (256B)
#define FLAGLINE 16
#define NCOLS 32     // gate-cols per block tile
#define NHC  8       // h-cols per block (NCOLS/4)
#define NT   2       // N-tiles of 16

template<int N> struct IC { static constexpr int value = N; };

__device__ __forceinline__ float sigmoidf_(float x) { return 1.f / (1.f + expf(-x)); }

// ---------------- conversion / init kernel ----------------
__global__ __launch_bounds__(256)
void convert_all(const float* __restrict__ x,
                 const float* __restrict__ h1in, const float* __restrict__ h2in,
                 bf16* __restrict__ xb, bf16* __restrict__ h1b0, bf16* __restrict__ h2b0,
                 unsigned* __restrict__ cnt)
{
    const size_t nXB = (size_t)T_ * B_ * KX_;   // 5242880
    const size_t nHC = (size_t)B_ * H_;         // 131072
    size_t idx = (size_t)blockIdx.x * 256 + threadIdx.x;

    if (idx < nXB) {                            // x [B][T][150] -> xb [T][B][160]
        size_t t = idx / (B_ * KX_);
        size_t r = idx - t * (B_ * KX_);
        size_t b = r / KX_, k = r - b * KX_;
        xb[idx] = (k < I_) ? (bf16)x[(b * T_ + t) * I_ + k] : (bf16)0.f;
        return;
    }
    idx -= nXB;
    if (idx < nHC) { h1b0[idx] = (bf16)h1in[idx]; return; }
    idx -= nHC;
    if (idx < nHC) { h2b0[idx] = (bf16)h2in[idx]; return; }
    idx -= nHC;
    if (idx < NLINES * CSTRIDE) cnt[idx] = 0u;
}

// ================= R13 primary: 8-wave rebalanced persistent kernel =========
// 256 blocks = 2 layers x 128 slices. layer=(bid>>3)&1, slice=(bid&7)|((bid>>4)<<3).
// L0: LDS = W1 (32x1280) + Wih2 slice (32x1024) = 144KB. epoch e in [0,T_]:
//   acc preloaded with x(e) part (overlapped into barrier e-1); dual-seg h1(e)
//   -> gates1 + p(e); publish p; epilogue h1(e+1) [e<T_].
// L1: LDS = Whh2 slice (32x1024) = 64KB. epoch e in [2,T_+1]:
//   prefetch p(e-1) regs; stream h2(e-2); acc += p; epilogue h2(e-1).
__global__ __launch_bounds__(512, 2)
void rnn_rebal8(const bf16* __restrict__ xb,
                bf16* __restrict__ h1b0, bf16* __restrict__ h1b1,
                bf16* __restrict__ h2b0, bf16* __restrict__ h2b1,
                float* __restrict__ p0, float* __restrict__ p1,
                const float* __restrict__ c1in, const float* __restrict__ c2in,
                const float* __restrict__ Wih1, const float* __restrict__ Whh1,
                const float* __restrict__ bih1, const float* __restrict__ bhh1,
                const float* __restrict__ Wih2, const float* __restrict__ Whh2,
                const float* __restrict__ bih2, const float* __restrict__ bhh2,
                const float* __restrict__ Wfc, const float* __restrict__ bfc,
                float* __restrict__ out, unsigned* __restrict__ cnt, int nblk)
{
    extern __shared__ bf16 lds[];
    __shared__ __align__(16) bf16 hst[8][16][NHC];   // epilogue staging

    const int tid   = threadIdx.x;
    const int bid   = blockIdx.x;
    const int layer = (bid >> 3) & 1;
    const int slice = (bid & 7) | ((bid >> 4) << 3);
    const int n0h   = slice * NHC;
    const int arr_per_line = nblk >> 4;          // 16 lines x 16 blocks
    bf16* ldsP = lds + 32 * K1LDS;               // L0's Wih2 region

    // ---- stage weights fp32->bf16 into swizzled LDS (once) ----
    if (layer == 0) {
        {   // W1 region: 32 rows x K1LDS (x [0,160), h1 [160,1184), pad)
            const int cpr = K1LDS >> 3;           // 160
            const int total = NCOLS * cpr;
            for (int ci = tid; ci < total; ci += 512) {
                int r = ci / cpr, c = ci - r * cpr;
                int g = r / NHC, j = r - g * NHC;
                int grow = (g << 10) + n0h + j;
                int k0 = c << 3;
                float v[8];
#pragma unroll
                for (int u = 0; u < 8; ++u) {
                    int k = k0 + u;
                    v[u] = (k < I_) ? Wih1[(size_t)grow * I_ + k]
                         : (k < KX_) ? 0.f
                         : (k < KX_ + H_) ? Whh1[(size_t)grow * H_ + (k - KX_)] : 0.f;
                }
                int cs = (c & ~15) | ((c ^ r) & 15);
                bf16* dst = lds + (size_t)r * K1LDS + (cs << 3);
#pragma unroll
                for (int u = 0; u < 8; ++u) dst[u] = (bf16)v[u];
            }
        }
        {   // Wih2 region: 32 rows x KP
            const int cpr = KP >> 3;              // 128
            const int total = NCOLS * cpr;
            for (int ci = tid; ci < total; ci += 512) {
                int r = ci / cpr, c = ci - r * cpr;
                int g = r / NHC, j = r - g * NHC;
                int grow = (g << 10) + n0h + j;
                int k0 = c << 3;
                float v[8];
#pragma unroll
                for (int u = 0; u < 8; ++u) v[u] = Wih2[(size_t)grow * H_ + k0 + u];
                int cs = (c & ~15) | ((c ^ r) & 15);
                bf16* dst = ldsP + (size_t)r * KP + (cs << 3);
#pragma unroll
                for (int u = 0; u < 8; ++u) dst[u] = (bf16)v[u];
            }
        }
    } else {
        // Whh2 region: 32 rows x KP
        const int cpr = KP >> 3;
        const int total = NCOLS * cpr;
        for (int ci = tid; ci < total; ci += 512) {
            int r = ci / cpr, c = ci - r * cpr;
            int g = r / NHC, j = r - g * NHC;
            int grow = (g << 10) + n0h + j;
            int k0 = c << 3;
            float v[8];
#pragma unroll
            for (int u = 0; u < 8; ++u) v[u] = Whh2[(size_t)grow * H_ + k0 + u];
            int cs = (c & ~15) | ((c ^ r) & 15);
            bf16* dst = lds + (size_t)r * KP + (cs << 3);
#pragma unroll
            for (int u = 0; u < 8; ++u) dst[u] = (bf16)v[u];
        }
    }
    __syncthreads();

    const int lane = tid & 63;
    const int wv   = tid >> 6;          // 0..7
    const int jj   = lane & (NHC - 1);
    const int quad = lane >> 4;

    float4 bias;
    {
        const float* bi = layer ? bih2 : bih1;
        const float* bh = layer ? bhh2 : bhh1;
        int col = n0h + jj;
        bias.x = bi[col] + bh[col];
        bias.y = bi[col + H_] + bh[col + H_];
        bias.z = bi[col + 2 * H_] + bh[col + 2 * H_];
        bias.w = bi[col + 3 * H_] + bh[col + 3 * H_];
    }

    float creg[2];
    {
        const float* cin = layer ? c2in : c1in;
        int dup = (lane >> 3) & 1;
#pragma unroll
        for (int rp = 0; rp < 2; ++rp) {
            int row = wv * 16 + quad * 4 + rp * 2 + dup;
            creg[rp] = cin[(size_t)row * H_ + n0h + jj];
        }
    }

    floatx4 acc[NT];
    floatx4 pacc[NT];

    // generic single-target K-segment (sched_barrier pin)
    auto seg1 = [&](const bf16* A, int ldA, const bf16* Bb, int ldB,
                    auto nksC, int ksBase) {
        constexpr int NKS = decltype(nksC)::value;
        constexpr int CH  = NKS < 16 ? NKS : 16;
        const int arow = wv * 16 + (lane & 15);
        const bf16* a0 = A + (size_t)arow * ldA + quad * 8;
        for (int blk = 0; blk < NKS; blk += CH) {
            bf16x8 a0r[CH];
#pragma unroll
            for (int i = 0; i < CH; ++i)
                a0r[i] = *(const bf16x8*)(a0 + (blk + i) * 32);
            __builtin_amdgcn_sched_barrier(0);
#pragma unroll
            for (int i = 0; i < CH; ++i) {
                int c = (ksBase + blk + i) * 4 + quad;
#pragma unroll
                for (int t = 0; t < NT; ++t) {
                    int r = t * 16 + (lane & 15);
                    int cs = (c & ~15) | ((c ^ r) & 15);
                    bf16x8 bfr = *(const bf16x8*)(Bb + (size_t)r * ldB + (cs << 3));
                    acc[t] = __builtin_amdgcn_mfma_f32_16x16x32_bf16(a0r[i], bfr, acc[t], 0, 0, 0);
                }
            }
        }
    };

    // dual-target h1-segment (L0): gates1 into acc (W1, ksBase 5) AND
    // p into pacc (Wih2, ksBase 0) from the SAME A stream.
    auto segDual = [&](const bf16* A) {
        const int arow = wv * 16 + (lane & 15);
        const bf16* a0 = A + (size_t)arow * H_ + quad * 8;
        for (int blk = 0; blk < 32; blk += 16) {
            bf16x8 a0r[16];
#pragma unroll
            for (int i = 0; i < 16; ++i)
                a0r[i] = *(const bf16x8*)(a0 + (blk + i) * 32);
            __builtin_amdgcn_sched_barrier(0);
#pragma unroll
            for (int i = 0; i < 16; ++i) {
                int ig = blk + i;
                int c1 = (5 + ig) * 4 + quad;
                int cp = ig * 4 + quad;
#pragma unroll
                for (int t = 0; t < NT; ++t) {
                    int r = t * 16 + (lane & 15);
                    int cs1 = (c1 & ~15) | ((c1 ^ r) & 15);
                    bf16x8 b1 = *(const bf16x8*)(lds + (size_t)r * K1LDS + (cs1 << 3));
                    acc[t] = __builtin_amdgcn_mfma_f32_16x16x32_bf16(a0r[i], b1, acc[t], 0, 0, 0);
                    int csp = (cp & ~15) | ((cp ^ r) & 15);
                    bf16x8 bp = *(const bf16x8*)(ldsP + (size_t)r * KP + (csp << 3));
                    pacc[t] = __builtin_amdgcn_mfma_f32_16x16x32_bf16(a0r[i], bp, pacc[t], 0, 0, 0);
                }
            }
        }
    };

    // epilogue: shfl-gather gates, update creg, stage h to LDS, store h
    auto epilogue = [&](bf16* hw) {
        const int base = lane & 48;
#pragma unroll
        for (int r = 0; r < 4; ++r) {
            float vi = __shfl(acc[0][r], base + jj, 64);
            float vf = __shfl(acc[0][r], base + 8 + jj, 64);
            float vg = __shfl(acc[1][r], base + jj, 64);
            float vo = __shfl(acc[1][r], base + 8 + jj, 64);
            bool cond = (((lane >> 3) & 1) == (r & 1));
            int slot = r >> 1;
            if (cond) {
                float cv = creg[slot];
                float cn = sigmoidf_(vf + bias.y) * cv
                         + sigmoidf_(vi + bias.x) * tanhf(vg + bias.z);
                creg[slot] = cn;
                float hn = sigmoidf_(vo + bias.w) * tanhf(cn);
                hst[wv][quad * 4 + r][jj] = (bf16)hn;
            }
        }
        __syncthreads();
        if (lane < 32) {
            int row_l = lane >> 1, cg = lane & 1;
            ull v = *(const ull*)&hst[wv][row_l][cg * 4];
            __hip_atomic_store((ull*)(hw + (size_t)(wv * 16 + row_l) * H_ + n0h + cg * 4),
                               v, __ATOMIC_RELAXED, __HIP_MEMORY_SCOPE_AGENT);
        }
    };

    // prologue (L0): zero accs and pre-compute x(0) contribution
    if (layer == 0) {
#pragma unroll
        for (int t = 0; t < NT; ++t) {
            acc[t]  = (floatx4){0.f, 0.f, 0.f, 0.f};
            pacc[t] = (floatx4){0.f, 0.f, 0.f, 0.f};
        }
        seg1(xb, KX_, lds, K1LDS, IC<5>{}, 0);     // x(0)
    }

    for (int e = 0; e <= T_ + 1; ++e) {
        if (layer == 0 && e <= T_) {
            // acc holds x(e) part (preloaded); dual-seg adds h1(e) part + p(e)
            const bf16* h1r = (e & 1) ? h1b1 : h1b0;          // h1^(e)
            segDual(h1r);

            // publish p(e) slice (f32, relaxed-agent write-through)
            float* pw = ((e & 1) ? p1 : p0) + (size_t)slice * B_ * NCOLS;
#pragma unroll
            for (int t = 0; t < NT; ++t)
#pragma unroll
                for (int r = 0; r < 4; ++r) {
                    int row = wv * 16 + quad * 4 + r;
                    __hip_atomic_store(pw + (size_t)row * NCOLS + t * 16 + (lane & 15),
                                       pacc[t][r], __ATOMIC_RELAXED, __HIP_MEMORY_SCOPE_AGENT);
                }

            if (e < T_) {
                bf16* hw = (e & 1) ? h1b0 : h1b1;              // h1^(e+1)
                epilogue(hw);
            }
        } else if (layer == 1 && e >= 2) {
#pragma unroll
            for (int t = 0; t < NT; ++t) acc[t] = (floatx4){0.f, 0.f, 0.f, 0.f};

            // prefetch p(e-1) slice into registers (post-fence: coherent)
            const float* pr = ((e & 1) ? p0 : p1) + (size_t)slice * B_ * NCOLS;
            float pv[NT][4];
#pragma unroll
            for (int t = 0; t < NT; ++t)
#pragma unroll
                for (int r = 0; r < 4; ++r) {
                    int row = wv * 16 + quad * 4 + r;
                    pv[t][r] = pr[(size_t)row * NCOLS + t * 16 + (lane & 15)];
                }

            const bf16* h2r = (e & 1) ? h2b1 : h2b0;           // h2^(e-2)
            seg1(h2r, H_, lds, KP, IC<32>{}, 0);

#pragma unroll
            for (int t = 0; t < NT; ++t)
#pragma unroll
                for (int r = 0; r < 4; ++r) acc[t][r] += pv[t][r];

            bf16* hw = (e & 1) ? h2b0 : h2b1;                  // h2^(e-1)
            epilogue(hw);
        }

        // ---- barrier: arrive -> overlapped x-prefetch (L0) -> detect -> fence
        asm volatile("s_waitcnt vmcnt(0)" ::: "memory");
        __syncthreads();
        const unsigned etag = (unsigned)(e + 1);
        if (tid == 0)
            __hip_atomic_fetch_add(cnt + (bid & 15) * CSTRIDE, 1u,
                                   __ATOMIC_RELAXED, __HIP_MEMORY_SCOPE_AGENT);
        // overlapped work in the barrier window: next-epoch x-seg on
        // immutable input (register results survive the fence)
        if (layer == 0 && e < T_) {
#pragma unroll
            for (int t = 0; t < NT; ++t) {
                acc[t]  = (floatx4){0.f, 0.f, 0.f, 0.f};
                pacc[t] = (floatx4){0.f, 0.f, 0.f, 0.f};
            }
            if (e + 1 < T_)
                seg1(xb + (size_t)(e + 1) * B_ * KX_, KX_, lds, K1LDS, IC<5>{}, 0);
        }
        if (bid == 0) {
            if (tid < 16) {
                const unsigned tgt = etag * (unsigned)arr_per_line;
                const unsigned* cp = cnt + tid * CSTRIDE;
                while (__hip_atomic_load(cp, __ATOMIC_RELAXED, __HIP_MEMORY_SCOPE_AGENT) < tgt)
                    __builtin_amdgcn_s_sleep(1);
            }
            if (tid == 0)
                __hip_atomic_store(cnt + FLAGLINE * CSTRIDE, etag,
                                   __ATOMIC_RELAXED, __HIP_MEMORY_SCOPE_AGENT);
        } else {
            if (tid == 0) {
                const unsigned* fp = cnt + FLAGLINE * CSTRIDE;
                while (__hip_atomic_load(fp, __ATOMIC_RELAXED, __HIP_MEMORY_SCOPE_AGENT) < etag)
                    __builtin_amdgcn_s_sleep(1);
            }
        }
        __syncthreads();
        // acquire (cache inv) by wave 0 only
        if (tid < 64)
            __builtin_amdgcn_fence(__ATOMIC_ACQUIRE, "agent");
        __syncthreads();
    }

    // ---- fused FC: out = h2^(256) @ Wfc^T + bfc ; h2^(256) is in h2b0 ----
    if (bid < B_) {
        const bf16* h2f = h2b0;
        for (int c = wv; c < C_; c += 8) {
            float a = 0.f;
            for (int k = lane; k < H_; k += 64)
                a += (float)h2f[(size_t)bid * H_ + k] * Wfc[(size_t)c * H_ + k];
#pragma unroll
            for (int off = 32; off; off >>= 1) a += __shfl_down(a, off, 64);
            if (lane == 0) out[bid * C_ + c] = a + bfc[c];
        }
    }
}

// ============ fallback: PROVEN R10 8-wave kernel (5140us, passed) ===========
// Same signature as primary; p0/p1 unused. Original R6 dataflow, 8-line barrier.
__global__ __launch_bounds__(512, 2)
void rnn_fallback8(const bf16* __restrict__ xb,
                   bf16* __restrict__ h1b0, bf16* __restrict__ h1b1,
                   bf16* __restrict__ h2b0, bf16* __restrict__ h2b1,
                   float* __restrict__ p0, float* __restrict__ p1,
                   const float* __restrict__ c1in, const float* __restrict__ c2in,
                   const float* __restrict__ Wih1, const float* __restrict__ Whh1,
                   const float* __restrict__ bih1, const float* __restrict__ bhh1,
                   const float* __restrict__ Wih2, const float* __restrict__ Whh2,
                   const float* __restrict__ bih2, const float* __restrict__ bhh2,
                   const float* __restrict__ Wfc, const float* __restrict__ bfc,
                   float* __restrict__ out, unsigned* __restrict__ cnt, int nblk)
{
    extern __shared__ bf16 lds[];
    __shared__ __align__(16) bf16 hst[8][16][NHC];

    const int tid   = threadIdx.x;
    const int bid   = blockIdx.x;
    const int layer = (bid >> 3) & 1;
    const int slice = (bid & 7) | ((bid >> 4) << 3);
    const int n0h   = slice * NHC;
    const int KLDS  = layer ? K2LDS : K1LDS;
    const int arr_per_line = nblk >> 3;

    {   // stage weights (R6 combined map)
        const int cpr = KLDS >> 3;
        const int total = NCOLS * cpr;
        for (int ci = tid; ci < total; ci += 512) {
            int r = ci / cpr, c = ci - r * cpr;
            int g = r / NHC, j = r - g * NHC;
            int grow = (g << 10) + n0h + j;
            int k0 = c << 3;
            float v[8];
#pragma unroll
            for (int u = 0; u < 8; ++u) {
                int k = k0 + u;
                if (layer == 0)
                    v[u] = (k < I_) ? Wih1[(size_t)grow * I_ + k]
                         : (k < KX_) ? 0.f
                         : (k < KX_ + H_) ? Whh1[(size_t)grow * H_ + (k - KX_)] : 0.f;
                else
                    v[u] = (k < H_) ? Wih2[(size_t)grow * H_ + k]
                                    : Whh2[(size_t)grow * H_ + (k - H_)];
            }
            int cs = (c & ~15) | ((c ^ r) & 15);
            bf16* dst = lds + (size_t)r * KLDS + (cs << 3);
#pragma unroll
            for (int u = 0; u < 8; ++u) dst[u] = (bf16)v[u];
        }
    }
    __syncthreads();

    const int lane = tid & 63;
    const int wv   = tid >> 6;
    const int jj   = lane & (NHC - 1);
    const int quad = lane >> 4;

    float4 bias;
    {
        const float* bi = layer ? bih2 : bih1;
        const float* bh = layer ? bhh2 : bhh1;
        int col = n0h + jj;
        bias.x = bi[col] + bh[col];
        bias.y = bi[col + H_] + bh[col + H_];
        bias.z = bi[col + 2 * H_] + bh[col + 2 * H_];
        bias.w = bi[col + 3 * H_] + bh[col + 3 * H_];
    }

    float creg[2];
    {
        const float* cin = layer ? c2in : c1in;
        int dup = (lane >> 3) & 1;
#pragma unroll
        for (int rp = 0; rp < 2; ++rp) {
            int row = wv * 16 + quad * 4 + rp * 2 + dup;
            creg[rp] = cin[(size_t)row * H_ + n0h + jj];
        }
    }

    floatx4 acc[NT];

    auto seg = [&](const bf16* A, int ldA, auto nksC, int ksBase) {
        constexpr int NKS = decltype(nksC)::value;
        constexpr int CH  = NKS < 16 ? NKS : 16;
        const int arow = wv * 16 + (lane & 15);
        const bf16* a0 = A + (size_t)arow * ldA + quad * 8;
        for (int blk = 0; blk < NKS; blk += CH) {
            bf16x8 a0r[CH];
#pragma unroll
            for (int i = 0; i < CH; ++i)
                a0r[i] = *(const bf16x8*)(a0 + (blk + i) * 32);
            __builtin_amdgcn_sched_barrier(0);
#pragma unroll
            for (int i = 0; i < CH; ++i) {
                int c = (ksBase + blk + i) * 4 + quad;
#pragma unroll
                for (int t = 0; t < NT; ++t) {
                    int r = t * 16 + (lane & 15);
                    int cs = (c & ~15) | ((c ^ r) & 15);
                    bf16x8 bfr = *(const bf16x8*)(lds + (size_t)r * KLDS + (cs << 3));
                    acc[t] = __builtin_amdgcn_mfma_f32_16x16x32_bf16(a0r[i], bfr, acc[t], 0, 0, 0);
                }
            }
        }
    };

    for (int e = 0; e <= T_; ++e) {
        const bool active = layer == 0 ? (e < T_) : (e >= 1);
        if (active) {
#pragma unroll
            for (int t = 0; t < NT; ++t) acc[t] = (floatx4){0.f, 0.f, 0.f, 0.f};

            const bf16* h1r = (e & 1) ? h1b1 : h1b0;
            if (layer == 0) {
                const bf16* xt = xb + (size_t)e * B_ * KX_;
                seg(xt, KX_, IC<5>{}, 0);
                seg(h1r, H_, IC<32>{}, 5);
            } else {
                const bf16* h2r = (e & 1) ? h2b0 : h2b1;
                seg(h1r, H_, IC<32>{}, 0);
                seg(h2r, H_, IC<32>{}, 32);
            }
            bf16* hw = (layer == 0) ? ((e & 1) ? h1b0 : h1b1)
                                    : ((e & 1) ? h2b1 : h2b0);

            const int base = lane & 48;
#pragma unroll
            for (int r = 0; r < 4; ++r) {
                float vi = __shfl(acc[0][r], base + jj, 64);
                float vf = __shfl(acc[0][r], base + 8 + jj, 64);
                float vg = __shfl(acc[1][r], base + jj, 64);
                float vo = __shfl(acc[1][r], base + 8 + jj, 64);
                bool cond = (((lane >> 3) & 1) == (r & 1));
                int slot = r >> 1;
                if (cond) {
                    float cv = creg[slot];
                    float cn = sigmoidf_(vf + bias.y) * cv
                             + sigmoidf_(vi + bias.x) * tanhf(vg + bias.z);
                    creg[slot] = cn;
                    float hn = sigmoidf_(vo + bias.w) * tanhf(cn);
                    hst[wv][quad * 4 + r][jj] = (bf16)hn;
                }
            }
            __syncthreads();
            if (lane < 32) {
                int row_l = lane >> 1, cg = lane & 1;
                ull v = *(const ull*)&hst[wv][row_l][cg * 4];
                __hip_atomic_store((ull*)(hw + (size_t)(wv * 16 + row_l) * H_ + n0h + cg * 4),
                                   v, __ATOMIC_RELAXED, __HIP_MEMORY_SCOPE_AGENT);
            }
        }

        asm volatile("s_waitcnt vmcnt(0)" ::: "memory");
        __syncthreads();
        const unsigned etag = (unsigned)(e + 1);
        if (bid == 0) {
            if (tid == 0)
                __hip_atomic_fetch_add(cnt, 1u, __ATOMIC_RELAXED, __HIP_MEMORY_SCOPE_AGENT);
            if (tid < 8) {
                const unsigned tgt = etag * (unsigned)arr_per_line;
                const unsigned* cp = cnt + tid * CSTRIDE;
                while (__hip_atomic_load(cp, __ATOMIC_RELAXED, __HIP_MEMORY_SCOPE_AGENT) < tgt)
                    __builtin_amdgcn_s_sleep(1);
            }
            if (tid == 0)
                __hip_atomic_store(cnt + 8 * CSTRIDE, etag,
                                   __ATOMIC_RELAXED, __HIP_MEMORY_SCOPE_AGENT);
        } else {
            if (tid == 0) {
                __hip_atomic_fetch_add(cnt + (bid & 7) * CSTRIDE, 1u,
                                       __ATOMIC_RELAXED, __HIP_MEMORY_SCOPE_AGENT);
                const unsigned* fp = cnt + 8 * CSTRIDE;
                while (__hip_atomic_load(fp, __ATOMIC_RELAXED, __HIP_MEMORY_SCOPE_AGENT) < etag)
                    __builtin_amdgcn_s_sleep(1);
            }
        }
        __syncthreads();
        if (tid < 64)
            __builtin_amdgcn_fence(__ATOMIC_ACQUIRE, "agent");
        __syncthreads();
    }

    if (bid < B_) {
        const bf16* h2f = h2b0;
        for (int c = wv; c < C_; c += 8) {
            float a = 0.f;
            for (int k = lane; k < H_; k += 64)
                a += (float)h2f[(size_t)bid * H_ + k] * Wfc[(size_t)c * H_ + k];
#pragma unroll
            for (int off = 32; off; off >>= 1) a += __shfl_down(a, off, 64);
            if (lane == 0) out[bid * C_ + c] = a + bfc[c];
        }
    }
}

extern "C" void kernel_launch(void* const* d_in, const int* in_sizes, int n_in,
                              void* d_out, int out_size, void* d_ws, size_t ws_size,
                              hipStream_t stream)
{
    const float* x    = (const float*)d_in[0];
    const float* h1in = (const float*)d_in[1];
    const float* c1in = (const float*)d_in[2];
    const float* h2in = (const float*)d_in[3];
    const float* c2in = (const float*)d_in[4];
    const float* Wih1 = (const float*)d_in[5];
    const float* Whh1 = (const float*)d_in[6];
    const float* bih1 = (const float*)d_in[7];
    const float* bhh1 = (const float*)d_in[8];
    const float* Wih2 = (const float*)d_in[9];
    const float* Whh2 = (const float*)d_in[10];
    const float* bih2 = (const float*)d_in[11];
    const float* bhh2 = (const float*)d_in[12];
    const float* Wfc  = (const float*)d_in[13];
    const float* bfc  = (const float*)d_in[14];
    float* out = (float*)d_out;

    // ws carve: base ~11.5MB always; p buffers (+4MB) only if ws fits
    const size_t szXB  = (size_t)T_ * B_ * KX_ * 2;        // 10485760
    const size_t szH   = (size_t)B_ * H_ * 2;              // 262144
    const size_t szCnt = (size_t)NLINES * CSTRIDE * 4;     // 8192
    const size_t szP   = (size_t)128 * B_ * NCOLS * 4;     // 2097152
    const size_t needBase  = szXB + 4 * szH + szCnt;
    const size_t needRebal = needBase + 2 * szP;

    char* p = (char*)d_ws;
    bf16* xb = (bf16*)p;    p += szXB;
    bf16* h1b0 = (bf16*)p;  p += szH;
    bf16* h1b1 = (bf16*)p;  p += szH;
    bf16* h2b0 = (bf16*)p;  p += szH;
    bf16* h2b1 = (bf16*)p;  p += szH;
    unsigned* cnt = (unsigned*)p;  p += szCnt;
    float* p0 = (float*)p;  p += szP;
    float* p1 = (float*)p;

    const size_t citems = (size_t)T_ * B_ * KX_ + 2 * (size_t)B_ * H_ + NLINES * CSTRIDE;
    convert_all<<<(int)((citems + 255) / 256), 256, 0, stream>>>(
        x, h1in, h2in, xb, h1b0, h2b0, cnt);

    int nblk = 256;
    void* args[] = { &xb, &h1b0, &h1b1, &h2b0, &h2b1, &p0, &p1,
                     (void*)&c1in, (void*)&c2in,
                     (void*)&Wih1, (void*)&Whh1, (void*)&bih1, (void*)&bhh1,
                     (void*)&Wih2, (void*)&Whh2, (void*)&bih2, (void*)&bhh2,
                     (void*)&Wfc, (void*)&bfc, &out, &cnt, &nblk };

    hipError_t err = hipErrorOutOfMemory;
    if (ws_size >= needRebal) {
        const unsigned ldsRebal = (unsigned)(32 * K1LDS + 32 * KP) * 2u;  // 147456
        if (hipFuncSetAttribute((const void*)rnn_rebal8,
                                hipFuncAttributeMaxDynamicSharedMemorySize,
                                (int)ldsRebal) == hipSuccess) {
            err = hipLaunchCooperativeKernel((const void*)rnn_rebal8,
                                             dim3(256), dim3(512), args,
                                             ldsRebal, stream);
        }
    }
    if (err != hipSuccess) {
        (void)hipGetLastError();
        (void)hipFuncSetAttribute((const void*)rnn_fallback8,
                                  hipFuncAttributeMaxDynamicSharedMemorySize, 131072);
        (void)hipLaunchCooperativeKernel((const void*)rnn_fallback8,
                                         dim3(256), dim3(512), args,
                                         131072u, stream);
    }
}